// Round 8
// baseline (421.610 us; speedup 1.0000x reference)
//
#include <hip/hip_runtime.h>
#include <stdint.h>

typedef unsigned int u32;
typedef unsigned long long u64;
typedef unsigned char u8;

#define NIMG 64
#define W0   518
#define H0   518
#define HW   268324
#define HW4  67081
#define BPI  32
#define NB0  33
#define N1 67081
#define CAP 32768
#define LCAP 1024

// ---- workspace layout ----
#define OFF_CNT   0ULL        // u32[64]
#define OFF_CCNT  256ULL      // u32[128]
#define OFF_NBL   768ULL      // u32[128]
#define OFF_RHO   1280ULL     // double[64]
#define OFF_STOT  1792ULL     // double[128]
#define OFF_SBL   2816ULL     // double[128]
#define OFF_GI0   3840ULL     // double[256]
#define OFF_GI1   5888ULL
#define OFF_GI2   7936ULL
#define OFF_GI3   9984ULL
#define OFF_TKT   12032ULL    // u32 ticket
#define ZERO_END  12288ULL    // zero 3072 u32
#define OFF_MED   12288ULL    // float[128]
#define OFF_SCI   12800ULL    // float[128]
#define OFF_SELW  13312ULL    // u32[256]
#define OFF_SWF   14336ULL    // float[256]
#define OFF_CAND  15360ULL                    // float[128][CAP]
#define OFF_MU8   (OFF_CAND + 16777216ULL)    // u8[64*HW]
#define OFF_P1    (OFF_MU8 + 17172736ULL)     // float[64*N1]
#define OFF_M1    (OFF_P1 + 17172736ULL)      // u8[64*N1]

__device__ __forceinline__ u32 f2key(float f) {
  u32 u = __float_as_uint(f);
  return (u & 0x80000000u) ? ~u : (u | 0x80000000u);
}
__device__ __forceinline__ float key2f(u32 k) {
  u32 u = (k & 0x80000000u) ? (k & 0x7fffffffu) : ~k;
  return __uint_as_float(u);
}

// block rank-find over LDS hist h[2048] (8 bins/thread); wave-scan, 2 barriers.
__device__ void blk_rankfind(u32* h, u32 target, bool enable, u32* outBin, u32* outRank)
{
  int b0 = threadIdx.x * 8;
  u32 s = 0;
  for (int j = 0; j < 8; j++) s += h[b0 + j];
  u32 x = s;
  int lane = threadIdx.x & 63;
  for (int o = 1; o < 64; o <<= 1) {
    u32 v = __shfl_up(x, o, 64);
    if (lane >= o) x += v;
  }
  __shared__ u32 wsum[4];
  int wv = threadIdx.x >> 6;
  if (lane == 63) wsum[wv] = x;
  __syncthreads();
  u32 woff = 0;
  for (int w = 0; w < wv; w++) woff += wsum[w];
  u32 cum = woff + x - s;
  for (int j = 0; j < 8; j++) {
    u32 v = h[b0 + j];
    if (enable && target >= cum && target < cum + v) { *outBin = (u32)(b0 + j); *outRank = target - cum; }
    cum += v;
  }
  __syncthreads();
}

// ---------- sample window + zero accumulators ----------
__global__ __launch_bounds__(256) void k_sample(const float* __restrict__ p,
    const float* __restrict__ y, u32* __restrict__ selw, float* __restrict__ swf,
    u32* __restrict__ zbase)
{
  int t = blockIdx.x, img = t >> 1;
  if (t == 0) {
    for (int i = threadIdx.x; i < 3072; i += 256) zbase[i] = 0;
  }
  const float* src = ((t & 1) ? y : p) + (size_t)img * HW;
  __shared__ u32 h[2048];
  __shared__ u32 bLo, rT, bHi;
  if (threadIdx.x == 0) { bLo = 0; bHi = 2047; }
  for (int i = threadIdx.x; i < 2048; i += 256) h[i] = 0;
  __syncthreads();
  for (int j = 0; j < 16; j++) {
    int s = threadIdx.x * 16 + j;
    float v = src[s * 65 + 32];
    atomicAdd(&h[f2key(v) >> 21], 1u);
  }
  __syncthreads();
  blk_rankfind(h, 1919u, true, &bLo, &rT);
  blk_rankfind(h, 2175u, true, &bHi, &rT);
  if (threadIdx.x == 0) {
    u32 k0 = bLo << 21;
    u32 k1 = (bHi >= 2047u) ? 0xFFFFFFFFu : ((bHi + 1u) << 21);
    selw[2 * t + 0] = k0;
    selw[2 * t + 1] = k1;
    float f0 = (k0 <= 0x007FFFFFu) ? __uint_as_float(0xFF800000u) : key2f(k0);
    float f1 = (k1 >= 0xFF800000u) ? __uint_as_float(0x7F800000u) : key2f(k1);
    swf[2 * t + 0] = f0;
    swf[2 * t + 1] = f1;
  }
}

// ---------- single full scan: mask write, cnt, Stot, below stats, capture ----------
__global__ __launch_bounds__(256) void k_scan0(const float4* __restrict__ p,
    const float4* __restrict__ y, const int4* __restrict__ m,
    uchar4* __restrict__ mu4, const float* __restrict__ swf,
    float* __restrict__ cand, u32* __restrict__ ccnt, u32* __restrict__ cnt,
    double* __restrict__ Stot, u32* __restrict__ Nbl, double* __restrict__ Sbl)
{
  __shared__ float capP[LCAP], capY[LCAP];
  __shared__ u32 nP, nY, baseP, baseY;
  if (threadIdx.x == 0) { nP = 0; nY = 0; }
  __syncthreads();
  int img = blockIdx.x / BPI, blk = blockIdx.x % BPI;
  float f0P = swf[img * 4 + 0], f1P = swf[img * 4 + 1];
  float f0Y = swf[img * 4 + 2], f1Y = swf[img * 4 + 3];
  const float4* pb = p + (size_t)img * HW4;
  const float4* yb = y + (size_t)img * HW4;
  const int4* mb = m + (size_t)img * HW4;
  uchar4* mo = mu4 + (size_t)img * HW4;
  int lc = 0, nBp = 0, nBy = 0;
  float sTp = 0.f, sBp = 0.f, sTy = 0.f, sBy = 0.f;

#define PEL(mm, vp, vy) if (mm) { lc++; \
      sTp += vp; \
      if (vp < f0P) { nBp++; sBp += vp; } \
      else if (vp < f1P) { u32 ix = atomicAdd(&nP, 1u); if (ix < LCAP) capP[ix] = vp; } \
      sTy += vy; \
      if (vy < f0Y) { nBy++; sBy += vy; } \
      else if (vy < f1Y) { u32 ix = atomicAdd(&nY, 1u); if (ix < LCAP) capY[ix] = vy; } }

  const int S = BPI * 256;
  int i = blk * 256 + threadIdx.x;
  for (; i + S < HW4; i += 2 * S) {
    float4 pa = pb[i], pc = pb[i + S];
    float4 ya = yb[i], yc = yb[i + S];
    int4 ma = mb[i], mc = mb[i + S];
    uchar4 wa, wc;
    wa.x = ma.x ? 1 : 0; wa.y = ma.y ? 1 : 0; wa.z = ma.z ? 1 : 0; wa.w = ma.w ? 1 : 0;
    wc.x = mc.x ? 1 : 0; wc.y = mc.y ? 1 : 0; wc.z = mc.z ? 1 : 0; wc.w = mc.w ? 1 : 0;
    mo[i] = wa; mo[i + S] = wc;
    PEL(wa.x, pa.x, ya.x) PEL(wa.y, pa.y, ya.y) PEL(wa.z, pa.z, ya.z) PEL(wa.w, pa.w, ya.w)
    PEL(wc.x, pc.x, yc.x) PEL(wc.y, pc.y, yc.y) PEL(wc.z, pc.z, yc.z) PEL(wc.w, pc.w, yc.w)
  }
  if (i < HW4) {
    float4 pv = pb[i]; float4 yv = yb[i]; int4 mv = mb[i];
    uchar4 mw; mw.x = mv.x ? 1 : 0; mw.y = mv.y ? 1 : 0; mw.z = mv.z ? 1 : 0; mw.w = mv.w ? 1 : 0;
    mo[i] = mw;
    PEL(mw.x, pv.x, yv.x) PEL(mw.y, pv.y, yv.y) PEL(mw.z, pv.z, yv.z) PEL(mw.w, pv.w, yv.w)
  }
#undef PEL

  __syncthreads();
  if (threadIdx.x == 0) {
    u32 np = nP, ny = nY;
    u32 addP = (np > (u32)LCAP) ? (u32)(CAP + 1) : np;
    u32 addY = (ny > (u32)LCAP) ? (u32)(CAP + 1) : ny;
    baseP = atomicAdd(&ccnt[img * 2 + 0], addP);
    baseY = atomicAdd(&ccnt[img * 2 + 1], addY);
  }
  __syncthreads();
  {
    u32 np = min(nP, (u32)LCAP), ny = min(nY, (u32)LCAP);
    float* cp = cand + (size_t)(img * 2 + 0) * CAP;
    float* cy = cand + (size_t)(img * 2 + 1) * CAP;
    for (u32 k = threadIdx.x; k < np; k += 256) { u32 g = baseP + k; if (g < CAP) cp[g] = capP[k]; }
    for (u32 k = threadIdx.x; k < ny; k += 256) { u32 g = baseY + k; if (g < CAP) cy[g] = capY[k]; }
  }
  double v0 = (double)sTp, v1 = (double)sBp, v2 = (double)sTy, v3 = (double)sBy;
  double v4 = (double)lc, v5 = (double)nBp, v6 = (double)nBy;
  for (int o = 32; o; o >>= 1) {
    v0 += __shfl_down(v0, o, 64); v1 += __shfl_down(v1, o, 64);
    v2 += __shfl_down(v2, o, 64); v3 += __shfl_down(v3, o, 64);
    v4 += __shfl_down(v4, o, 64); v5 += __shfl_down(v5, o, 64);
    v6 += __shfl_down(v6, o, 64);
  }
  __shared__ double sh[7][4];
  int lane = threadIdx.x & 63, wv = threadIdx.x >> 6;
  if (lane == 0) { sh[0][wv]=v0; sh[1][wv]=v1; sh[2][wv]=v2; sh[3][wv]=v3; sh[4][wv]=v4; sh[5][wv]=v5; sh[6][wv]=v6; }
  __syncthreads();
  if (threadIdx.x == 0) {
    double a[7];
    for (int k = 0; k < 7; k++) a[k] = sh[k][0] + sh[k][1] + sh[k][2] + sh[k][3];
    atomicAdd(&Stot[img * 2 + 0], a[0]);
    atomicAdd(&Sbl [img * 2 + 0], a[1]);
    atomicAdd(&Stot[img * 2 + 1], a[2]);
    atomicAdd(&Sbl [img * 2 + 1], a[3]);
    atomicAdd(&cnt[img], (u32)a[4]);
    atomicAdd(&Nbl[img * 2 + 0], (u32)a[5]);
    atomicAdd(&Nbl[img * 2 + 1], (u32)a[6]);
  }
}

// ---------- exact median + MAD (fast path; integrated exact fallback) ----------
__global__ __launch_bounds__(256) void k_med2(const float* __restrict__ cand,
    const u32* __restrict__ ccnt, const u32* __restrict__ cnt,
    const u32* __restrict__ Nbl, const double* __restrict__ Stot,
    const double* __restrict__ Sbl, const u32* __restrict__ selw,
    const float* __restrict__ pf, const float* __restrict__ yf,
    const u8* __restrict__ mu8, float* __restrict__ med, float* __restrict__ sci)
{
  int t = blockIdx.x, img = t >> 1;
  u32 c = cnt[img];
  if (c == 0) {
    if (threadIdx.x == 0) { med[t] = 0.f; sci[t] = 1e8f; }
    return;
  }
  u32 ntot = ccnt[t];
  u32 target0 = (c - 1) >> 1;
  u32 nb = Nbl[t];
  bool valid = (ntot <= (u32)CAP) && (target0 >= nb) && ((target0 - nb) < ntot);
  __shared__ u32 h[2048];
  __shared__ u32 sBin, sRank;
  if (threadIdx.x == 0) { sBin = 0; sRank = 0; }
  int lane = threadIdx.x & 63, wv = threadIdx.x >> 6;
  __shared__ double sh2[2][4];

  if (valid) {
    u32 n = ntot;
    const float* cd = cand + (size_t)t * CAP;
    u32 curLo = selw[2 * t + 0];
    u64 curR = (u64)selw[2 * t + 1] - (u64)curLo;
    u32 tgt = target0 - nb;
    for (int pass = 0; pass < 3; pass++) {
      int s = 0;
      while (((curR - 1) >> s) >= 2048) s++;
      for (int i = threadIdx.x; i < 2048; i += 256) h[i] = 0;
      __syncthreads();
      for (u32 j = threadIdx.x; j < n; j += 256) {
        u32 k = f2key(cd[j]);
        if (k >= curLo && (u64)(k - curLo) < curR)
          atomicAdd(&h[(k - curLo) >> s], 1u);
      }
      __syncthreads();
      blk_rankfind(h, tgt, true, &sBin, &sRank);
      curLo = curLo + (sBin << s);
      curR = (u64)1 << s;
      tgt = sRank;
      if (s == 0) break;
    }
    float mv = key2f(curLo);
    u32 nlt2 = 0; float slt2 = 0.f;
    for (u32 j = threadIdx.x; j < n; j += 256) {
      float v = cd[j];
      if (v < mv) { nlt2++; slt2 += v; }
    }
    double v0 = (double)nlt2, v1 = (double)slt2;
    for (int o = 32; o; o >>= 1) { v0 += __shfl_down(v0, o, 64); v1 += __shfl_down(v1, o, 64); }
    if (lane == 0) { sh2[0][wv] = v0; sh2[1][wv] = v1; }
    __syncthreads();
    if (threadIdx.x == 0) {
      double nl = (double)nb + sh2[0][0] + sh2[0][1] + sh2[0][2] + sh2[0][3];
      double sl = Sbl[t] + sh2[1][0] + sh2[1][1] + sh2[1][2] + sh2[1][3];
      double md = (double)mv;
      double mad = Stot[t] + 2.0 * md * nl - 2.0 * sl - md * (double)c;
      double sc = mad / (double)c + 1e-8;
      med[t] = mv; sci[t] = (float)(1.0 / sc);
    }
  } else {
    const float* src = ((t & 1) ? yf : pf) + (size_t)img * HW;
    const u8* mk = mu8 + (size_t)img * HW;
    u32 curLo = 0; u64 curR = (u64)1 << 32; u32 tgt = target0;
    for (int pass = 0; pass < 4; pass++) {
      int s = 0;
      while (((curR - 1) >> s) >= 2048) s++;
      for (int i = threadIdx.x; i < 2048; i += 256) h[i] = 0;
      __syncthreads();
      for (u32 j = threadIdx.x; j < (u32)HW; j += 256) {
        if (mk[j]) {
          u32 k = f2key(src[j]);
          if (k >= curLo && (u64)(k - curLo) < curR)
            atomicAdd(&h[(k - curLo) >> s], 1u);
        }
      }
      __syncthreads();
      blk_rankfind(h, tgt, true, &sBin, &sRank);
      curLo = curLo + (sBin << s);
      curR = (u64)1 << s;
      tgt = sRank;
      if (s == 0) break;
    }
    float mv = key2f(curLo);
    double nl = 0.0, sl = 0.0;
    for (u32 j = threadIdx.x; j < (u32)HW; j += 256) {
      if (mk[j]) {
        float v = src[j];
        if (v < mv) { nl += 1.0; sl += (double)v; }
      }
    }
    for (int o = 32; o; o >>= 1) { nl += __shfl_down(nl, o, 64); sl += __shfl_down(sl, o, 64); }
    if (lane == 0) { sh2[0][wv] = nl; sh2[1][wv] = sl; }
    __syncthreads();
    if (threadIdx.x == 0) {
      double nlT = sh2[0][0] + sh2[0][1] + sh2[0][2] + sh2[0][3];
      double slT = sh2[1][0] + sh2[1][1] + sh2[1][2] + sh2[1][3];
      double md = (double)mv;
      double mad = Stot[t] + 2.0 * md * nlT - 2.0 * slT - md * (double)c;
      double sc = mad / (double)c + 1e-8;
      med[t] = mv; sci[t] = (float)(1.0 / sc);
    }
  }
}

// ---------- fused: D in registers + rho + scale-0 grad + pool0 ----------
__global__ __launch_bounds__(320) void k_fuse0(const float* __restrict__ p,
    const float* __restrict__ y, const u8* __restrict__ mu,
    const float* __restrict__ medv, const float* __restrict__ sciv,
    float* __restrict__ P1, u8* __restrict__ M1,
    double* __restrict__ rho, double* __restrict__ gI)
{
  int img = blockIdx.x / NB0, band = blockIdx.x % NB0;
  float mp = medv[img * 2 + 0], my = medv[img * 2 + 1];
  float ap = sciv[img * 2 + 0], ay = sciv[img * 2 + 1];
  const float* pb = p + (size_t)img * HW;
  const float* yb = y + (size_t)img * HW;
  const u8*   mb = mu + (size_t)img * HW;
  int ra = band * 16;
  int rb = min(ra + 16, H0);
  int rend = (rb < H0) ? rb + 1 : H0;
  int oc = threadIdx.x;
  bool act = oc < 259;
  int cc = act ? 2 * oc : 516;
  bool vn = act && (2 * oc + 2 < W0);
  int lane = threadIdx.x & 63;
  bool edge = (lane == 63);
  float gx = 0.f, gy = 0.f, rr = 0.f;
  int cx = 0, cy = 0;
  float pd0 = 0.f, pd1 = 0.f; u8 pm0 = 0, pm1 = 0;
  float2 pv0, yv0, pv1, yv1;
  uchar2 mv0, mv1;
  {
    size_t a0 = (size_t)ra * W0 + cc;
    pv0 = *(const float2*)(pb + a0); yv0 = *(const float2*)(yb + a0); mv0 = *(const uchar2*)(mb + a0);
    if (ra + 1 < rend) {
      size_t a1 = a0 + W0;
      pv1 = *(const float2*)(pb + a1); yv1 = *(const float2*)(yb + a1); mv1 = *(const uchar2*)(mb + a1);
    } else { pv1 = pv0; yv1 = yv0; mv1 = mv0; }
  }
  for (int r = ra; r < rend; ++r) {
    float2 pv2 = pv1, yv2 = yv1; uchar2 mv2 = mv1;
    if (r + 2 < rend) {
      size_t a2 = (size_t)(r + 2) * W0 + cc;
      pv2 = *(const float2*)(pb + a2); yv2 = *(const float2*)(yb + a2); mv2 = *(const uchar2*)(mb + a2);
    }
    bool core = r < rb;
    float d0 = (pv0.x - mp) * ap - (yv0.x - my) * ay;
    float d1 = (pv0.y - mp) * ap - (yv0.y - my) * ay;
    u8 m0 = mv0.x, m1 = mv0.y;
    float dn = __shfl_down(d0, 1, 64);
    int mn = __shfl_down((int)m0, 1, 64);
    if (vn && edge) {
      size_t a = (size_t)r * W0 + (size_t)cc + 2;
      float pnb = pb[a], ynb = yb[a];
      dn = (pnb - mp) * ap - (ynb - my) * ay;
      mn = mb[a];
    }
    if (act) {
      float f0 = (float)m0, f1 = (float)m1;
      if (core) {
        gx += f0 * f1 * fabsf(d1 - d0); cx += (int)(m0 & m1);
        if (vn) { float fn = (float)mn; gx += f1 * fn * fabsf(dn - d1); cx += (m1 && mn) ? 1 : 0; }
        rr += f0 * fabsf(d0) + f1 * fabsf(d1);
      }
      if (r > ra) {
        gy += f0 * (float)pm0 * fabsf(d0 - pd0); cy += (int)(m0 & pm0);
        gy += f1 * (float)pm1 * fabsf(d1 - pd1); cy += (int)(m1 & pm1);
      }
      if (core && (r & 1)) {
        size_t o = (size_t)img * N1 + (size_t)(r >> 1) * 259 + oc;
        P1[o] = 0.25f * (pd0 + pd1 + d0 + d1);
        M1[o] = (u8)((pm0 | pm1 | m0 | m1) ? 1 : 0);
      }
    }
    pd0 = d0; pd1 = d1; pm0 = m0; pm1 = m1;
    pv0 = pv1; yv0 = yv1; mv0 = mv1;
    pv1 = pv2; yv1 = yv2; mv1 = mv2;
  }
  double v0 = (double)gx, v1 = (double)cx, v2 = (double)gy, v3 = (double)cy, v4 = (double)rr;
  for (int o = 32; o; o >>= 1) {
    v0 += __shfl_down(v0, o, 64); v1 += __shfl_down(v1, o, 64);
    v2 += __shfl_down(v2, o, 64); v3 += __shfl_down(v3, o, 64);
    v4 += __shfl_down(v4, o, 64);
  }
  __shared__ double sh[5][5];
  int wv = threadIdx.x >> 6;
  if (lane == 0) { sh[0][wv] = v0; sh[1][wv] = v1; sh[2][wv] = v2; sh[3][wv] = v3; sh[4][wv] = v4; }
  __syncthreads();
  if (threadIdx.x == 0) {
    double a0 = 0, a1 = 0, a2 = 0, a3 = 0, a4 = 0;
    for (int w = 0; w < 5; w++) { a0 += sh[0][w]; a1 += sh[1][w]; a2 += sh[2][w]; a3 += sh[3][w]; a4 += sh[4][w]; }
    atomicAdd(&gI[img * 4 + 0], a0);
    atomicAdd(&gI[img * 4 + 1], a1);
    atomicAdd(&gI[img * 4 + 2], a2);
    atomicAdd(&gI[img * 4 + 3], a3);
    atomicAdd(&rho[img], a4);
  }
}

// ---------- merged pyramid: gI1 (259) + LDS pool -> gI2 (129) + pool -> gI3 (64) + finalize ----------
__global__ __launch_bounds__(192) void k_gp12(const float* __restrict__ P1,
    const u8* __restrict__ M1, const double* __restrict__ rho,
    const u32* __restrict__ cnt, const double* __restrict__ gI0,
    double* __restrict__ gI1v, double* __restrict__ gI2v, double* __restrict__ gI3v,
    u32* __restrict__ ticket, float* __restrict__ out)
{
  const int Win = 259, Hin = 259;
  const int nb = 17;
  int img = blockIdx.x / nb, band = blockIdx.x % nb;
  const float* pb = P1 + (size_t)img * (Win * Hin);
  const u8*   mb = M1 + (size_t)img * (Win * Hin);
  int ra = band * 16;
  int rb = min(ra + 16, 258);                    // P1 pool boundary
  int rbx = (band == nb - 1) ? Hin : rb;         // gI1 x-grad ownership end
  int rendCore = (rbx < Hin) ? rbx + 1 : Hin;    // gI1 y-pairs iterate bound
  int rend = min(ra + 20, Hin);                  // +4 halo P1 rows (P2/P3 halos)
  if (rend < rendCore) rend = rendCore;
  int p2own0 = ra >> 1, p2own1 = rb >> 1;        // owned P2 rows [p2own0, p2own1)
  int p3own0 = 4 * band, p3own1 = min(4 * band + 4, 64);

  __shared__ float l2v[2][132];
  __shared__ u8    l2m[2][132];

  int oc = threadIdx.x;
  bool act = oc < 129;
  int c0 = act ? 2 * oc : 256;
  int c1 = c0 + 1, cnn = c0 + 2;
  bool vn = act && (cnn < Win);
  bool gyn = vn && (cnn >= 258);                 // P1 col 258 extra (thread 128)

  float g1x = 0, g1y = 0, g2x = 0, g2y = 0, g3x = 0, g3y = 0;
  int   c1x = 0, c1y = 0, c2x = 0, c2y = 0, c3x = 0, c3y = 0;

  float pd0 = 0, pd1 = 0, pdn = 0; u8 pm0 = 0, pm1 = 0, pmn = 0;
  float p2prev = 0; int m2prev = 0; bool have2 = false;
  float p3prev = 0; int m3prev = 0; bool have3 = false;

  for (int r = ra; r < rend; ++r) {
    int base = r * Win;
    float d0 = 0, d1 = 0, dn = 0; u8 m0 = 0, m1 = 0, mn = 0;
    if (act) {
      d0 = pb[base + c0]; d1 = pb[base + c1];
      m0 = mb[base + c0]; m1 = mb[base + c1];
      if (vn) { dn = pb[base + cnn]; mn = mb[base + cnn]; }
    }
    if (act && r < rbx) {
      if (m0 & m1) { g1x += fabsf(d1 - d0); c1x++; }
      if (vn && (m1 & mn)) { g1x += fabsf(dn - d1); c1x++; }
    }
    if (act && r > ra && r < rendCore) {
      if (m0 & pm0) { g1y += fabsf(d0 - pd0); c1y++; }
      if (m1 & pm1) { g1y += fabsf(d1 - pd1); c1y++; }
      if (gyn && (mn & pmn)) { g1y += fabsf(dn - pdn); c1y++; }
    }
    if (r & 1) {
      int j2 = r >> 1;                           // P2 row
      if (j2 < 129) {
        int buf = j2 & 1;
        float v2 = 0; u8 mm2 = 0;
        if (act) {
          v2 = 0.25f * (pd0 + pd1 + d0 + d1);
          mm2 = (u8)((pm0 | pm1 | m0 | m1) ? 1 : 0);
          l2v[buf][oc] = v2; l2m[buf][oc] = mm2;
        }
        __syncthreads();
        if (act && j2 >= p2own0 && j2 < p2own1 && oc < 128) {   // gI2 x on owned rows
          float vr = l2v[buf][oc + 1]; u8 mr = l2m[buf][oc + 1];
          if (mm2 & mr) { g2x += fabsf(vr - v2); c2x++; }
        }
        if (act && have2 && (j2 - 1) >= p2own0 && (j2 - 1) < p2own1) {  // gI2 y
          if (mm2 && m2prev) { g2y += fabsf(v2 - p2prev); c2y++; }
        }
        if ((j2 & 1) && threadIdx.x < 64) {       // P3 row i3 = j2>>1
          int i3 = j2 >> 1;
          int pbuf = buf ^ 1;
          int tc = 2 * threadIdx.x;
          float a = l2v[pbuf][tc], b = l2v[pbuf][tc + 1];
          float cf = l2v[buf][tc], df = l2v[buf][tc + 1];
          u8 ma_ = l2m[pbuf][tc], mb_ = l2m[pbuf][tc + 1];
          u8 mc_ = l2m[buf][tc],  md_ = l2m[buf][tc + 1];
          float v3 = 0.25f * (a + b + cf + df);
          int m3i = (ma_ | mb_ | mc_ | md_) ? 1 : 0;
          float vn3 = __shfl_down(v3, 1, 64);
          int   mn3 = __shfl_down(m3i, 1, 64);
          if (i3 >= p3own0 && i3 < p3own1) {
            if (threadIdx.x < 63 && m3i && mn3) { g3x += fabsf(vn3 - v3); c3x++; }
          }
          if (have3 && (i3 - 1) >= p3own0 && (i3 - 1) < p3own1) {
            if (m3i && m3prev) { g3y += fabsf(v3 - p3prev); c3y++; }
          }
          p3prev = v3; m3prev = m3i; have3 = true;
        }
        __syncthreads();
        if (act) { p2prev = v2; m2prev = mm2; have2 = true; }
      }
    }
    pd0 = d0; pd1 = d1; pdn = dn; pm0 = m0; pm1 = m1; pmn = mn;
  }

  double v[12] = {(double)g1x, (double)c1x, (double)g1y, (double)c1y,
                  (double)g2x, (double)c2x, (double)g2y, (double)c2y,
                  (double)g3x, (double)c3x, (double)g3y, (double)c3y};
  for (int o = 32; o; o >>= 1)
    for (int k = 0; k < 12; k++) v[k] += __shfl_down(v[k], o, 64);
  __shared__ double shr[12][3];
  int lane = threadIdx.x & 63, wv = threadIdx.x >> 6;
  if (lane == 0) for (int k = 0; k < 12; k++) shr[k][wv] = v[k];
  __syncthreads();
  if (threadIdx.x == 0) {
    for (int k = 0; k < 4; k++) {
      atomicAdd(&gI1v[img * 4 + k], shr[k][0] + shr[k][1] + shr[k][2]);
      atomicAdd(&gI2v[img * 4 + k], shr[4 + k][0] + shr[4 + k][1] + shr[4 + k][2]);
      atomicAdd(&gI3v[img * 4 + k], shr[8 + k][0] + shr[8 + k][1] + shr[8 + k][2]);
    }
  }
  // ---- finalize by last block (device-scope ticket) ----
  __threadfence();
  __shared__ u32 isLast;
  if (threadIdx.x == 0) {
    u32 old = atomicAdd(ticket, 1u);
    isLast = (old == (u32)(gridDim.x - 1)) ? 1u : 0u;
  }
  __syncthreads();
  if (isLast && threadIdx.x < 64) {
    __threadfence();
    int i = threadIdx.x;
    double vv[17];
    double c = cnt[i] ? (double)cnt[i] : 1.0;
    vv[0] = rho[i] / c;
    for (int j = 0; j < 4; j++) {
      vv[1 + j]  = gI0[i * 4 + j];                       // prior kernel: safe plain load
      vv[5 + j]  = atomicAdd(&gI1v[i * 4 + j], 0.0);     // same-kernel: coherent atomic read
      vv[9 + j]  = atomicAdd(&gI2v[i * 4 + j], 0.0);
      vv[13 + j] = atomicAdd(&gI3v[i * 4 + j], 0.0);
    }
    for (int o = 32; o; o >>= 1)
      for (int k = 0; k < 17; k++) vv[k] += __shfl_down(vv[k], o, 64);
    if (i == 0) {
      double ssi = vv[0] / (double)NIMG;
      double g = 0.0;
      for (int s = 0; s < 4; s++) {
        double gxs = vv[1 + s * 4 + 0], cxs = vv[1 + s * 4 + 1];
        double gys = vv[1 + s * 4 + 2], cys = vv[1 + s * 4 + 3];
        g += gxs / (cxs > 1.0 ? cxs : 1.0);
        g += gys / (cys > 1.0 ? cys : 1.0);
      }
      g /= 4.0;
      out[0] = (float)(ssi + 0.5 * g);
    }
  }
}

extern "C" void kernel_launch(void* const* d_in, const int* in_sizes, int n_in,
                              void* d_out, int out_size, void* d_ws, size_t ws_size,
                              hipStream_t stream) {
  (void)in_sizes; (void)n_in; (void)out_size; (void)ws_size;
  const float4* p4 = (const float4*)d_in[0];
  const float4* y4 = (const float4*)d_in[1];
  const int4* m4 = (const int4*)d_in[2];
  const float* pf = (const float*)d_in[0];
  const float* yf = (const float*)d_in[1];
  u8* ws = (u8*)d_ws;

  u32*    cnt  = (u32*)(ws + OFF_CNT);
  u32*    ccnt = (u32*)(ws + OFF_CCNT);
  u32*    Nbl  = (u32*)(ws + OFF_NBL);
  double* rho  = (double*)(ws + OFF_RHO);
  double* Stot = (double*)(ws + OFF_STOT);
  double* Sbl  = (double*)(ws + OFF_SBL);
  double* gI0  = (double*)(ws + OFF_GI0);
  double* gI1  = (double*)(ws + OFF_GI1);
  double* gI2  = (double*)(ws + OFF_GI2);
  double* gI3  = (double*)(ws + OFF_GI3);
  u32*    tkt  = (u32*)(ws + OFF_TKT);
  float*  med  = (float*)(ws + OFF_MED);
  float*  sci  = (float*)(ws + OFF_SCI);
  u32*    selw = (u32*)(ws + OFF_SELW);
  float*  swf  = (float*)(ws + OFF_SWF);
  float*  cand = (float*)(ws + OFF_CAND);
  u8*     mu8  = (u8*)(ws + OFF_MU8);
  float*  P1   = (float*)(ws + OFF_P1);
  u8*     M1   = (u8*)(ws + OFF_M1);

  k_sample<<<128, 256, 0, stream>>>(pf, yf, selw, swf, (u32*)ws);
  k_scan0<<<NIMG * BPI, 256, 0, stream>>>(p4, y4, m4, (uchar4*)mu8, swf, cand, ccnt, cnt, Stot, Nbl, Sbl);
  k_med2<<<128, 256, 0, stream>>>(cand, ccnt, cnt, Nbl, Stot, Sbl, selw, pf, yf, mu8, med, sci);
  k_fuse0<<<NIMG * NB0, 320, 0, stream>>>(pf, yf, mu8, med, sci, P1, M1, rho, gI0);
  k_gp12<<<NIMG * 17, 192, 0, stream>>>(P1, M1, rho, cnt, gI0, gI1, gI2, gI3, tkt, (float*)d_out);
}

// Round 9
// 367.745 us; speedup vs baseline: 1.1465x; 1.1465x over previous
//
#include <hip/hip_runtime.h>
#include <stdint.h>

typedef unsigned int u32;
typedef unsigned long long u64;
typedef unsigned char u8;

#define NIMG 64
#define W0   518
#define H0   518
#define HW   268324
#define HW4  67081
#define BPI  32
#define NB0  33
#define CAP 32768
#define LCAP 1024

// padded pyramid strides (even => aligned float2 loads)
#define W1S  260
#define H1   259
#define N1P  (W1S * H1)      // 67340
#define W2S  130
#define H2   129
#define N2P  (W2S * H2)      // 16770

// ---- workspace layout ----
#define OFF_CNT   0ULL        // u32[64]
#define OFF_CCNT  256ULL      // u32[128]
#define OFF_NBL   768ULL      // u32[128]
#define OFF_RHO   1280ULL     // double[64]
#define OFF_STOT  1792ULL     // double[128]
#define OFF_SBL   2816ULL     // double[128]
#define OFF_GI0   3840ULL     // double[256]
#define OFF_GI1   5888ULL
#define OFF_GI2   7936ULL
#define OFF_GI3   9984ULL
#define ZERO_END  12288ULL    // zero 3072 u32
#define OFF_MED   12288ULL    // float[128]
#define OFF_SCI   12800ULL    // float[128]
#define OFF_SELW  13312ULL    // u32[256]
#define OFF_SWF   14336ULL    // float[256]
#define OFF_CAND  15360ULL                    // float[128][CAP]
#define OFF_MU8   (OFF_CAND + 16777216ULL)    // u8[64*HW]
#define OFF_P1    (OFF_MU8 + 17172736ULL)     // float[64*N1P]
#define OFF_M1    (OFF_P1 + 17239040ULL)      // u8[64*N1P]
#define OFF_P2    (OFF_M1 + 4309760ULL)       // float[64*N2P]
#define OFF_M2    (OFF_P2 + 4293120ULL)       // u8[64*N2P]

__device__ __forceinline__ u32 f2key(float f) {
  u32 u = __float_as_uint(f);
  return (u & 0x80000000u) ? ~u : (u | 0x80000000u);
}
__device__ __forceinline__ float key2f(u32 k) {
  u32 u = (k & 0x80000000u) ? (k & 0x7fffffffu) : ~k;
  return __uint_as_float(u);
}

// block rank-find over LDS hist h[2048] (8 bins/thread); wave-scan, 2 barriers.
__device__ void blk_rankfind(u32* h, u32 target, bool enable, u32* outBin, u32* outRank)
{
  int b0 = threadIdx.x * 8;
  u32 s = 0;
  for (int j = 0; j < 8; j++) s += h[b0 + j];
  u32 x = s;
  int lane = threadIdx.x & 63;
  for (int o = 1; o < 64; o <<= 1) {
    u32 v = __shfl_up(x, o, 64);
    if (lane >= o) x += v;
  }
  __shared__ u32 wsum[4];
  int wv = threadIdx.x >> 6;
  if (lane == 63) wsum[wv] = x;
  __syncthreads();
  u32 woff = 0;
  for (int w = 0; w < wv; w++) woff += wsum[w];
  u32 cum = woff + x - s;
  for (int j = 0; j < 8; j++) {
    u32 v = h[b0 + j];
    if (enable && target >= cum && target < cum + v) { *outBin = (u32)(b0 + j); *outRank = target - cum; }
    cum += v;
  }
  __syncthreads();
}

// ---------- sample window + zero accumulators ----------
__global__ __launch_bounds__(256) void k_sample(const float* __restrict__ p,
    const float* __restrict__ y, u32* __restrict__ selw, float* __restrict__ swf,
    u32* __restrict__ zbase)
{
  int t = blockIdx.x, img = t >> 1;
  if (t == 0) {
    for (int i = threadIdx.x; i < 3072; i += 256) zbase[i] = 0;
  }
  const float* src = ((t & 1) ? y : p) + (size_t)img * HW;
  __shared__ u32 h[2048];
  __shared__ u32 bLo, rT, bHi;
  if (threadIdx.x == 0) { bLo = 0; bHi = 2047; }
  for (int i = threadIdx.x; i < 2048; i += 256) h[i] = 0;
  __syncthreads();
  for (int j = 0; j < 16; j++) {
    int s = threadIdx.x * 16 + j;
    float v = src[s * 65 + 32];
    atomicAdd(&h[f2key(v) >> 21], 1u);
  }
  __syncthreads();
  blk_rankfind(h, 1919u, true, &bLo, &rT);
  blk_rankfind(h, 2175u, true, &bHi, &rT);
  if (threadIdx.x == 0) {
    u32 k0 = bLo << 21;
    u32 k1 = (bHi >= 2047u) ? 0xFFFFFFFFu : ((bHi + 1u) << 21);
    selw[2 * t + 0] = k0;
    selw[2 * t + 1] = k1;
    float f0 = (k0 <= 0x007FFFFFu) ? __uint_as_float(0xFF800000u) : key2f(k0);
    float f1 = (k1 >= 0xFF800000u) ? __uint_as_float(0x7F800000u) : key2f(k1);
    swf[2 * t + 0] = f0;
    swf[2 * t + 1] = f1;
  }
}

// ---------- single full scan: mask write, cnt, Stot, below stats, capture ----------
__global__ __launch_bounds__(256) void k_scan0(const float4* __restrict__ p,
    const float4* __restrict__ y, const int4* __restrict__ m,
    uchar4* __restrict__ mu4, const float* __restrict__ swf,
    float* __restrict__ cand, u32* __restrict__ ccnt, u32* __restrict__ cnt,
    double* __restrict__ Stot, u32* __restrict__ Nbl, double* __restrict__ Sbl)
{
  __shared__ float capP[LCAP], capY[LCAP];
  __shared__ u32 nP, nY, baseP, baseY;
  if (threadIdx.x == 0) { nP = 0; nY = 0; }
  __syncthreads();
  int img = blockIdx.x / BPI, blk = blockIdx.x % BPI;
  float f0P = swf[img * 4 + 0], f1P = swf[img * 4 + 1];
  float f0Y = swf[img * 4 + 2], f1Y = swf[img * 4 + 3];
  const float4* pb = p + (size_t)img * HW4;
  const float4* yb = y + (size_t)img * HW4;
  const int4* mb = m + (size_t)img * HW4;
  uchar4* mo = mu4 + (size_t)img * HW4;
  int lc = 0, nBp = 0, nBy = 0;
  float sTp = 0.f, sBp = 0.f, sTy = 0.f, sBy = 0.f;

#define PEL(mm, vp, vy) if (mm) { lc++; \
      sTp += vp; \
      if (vp < f0P) { nBp++; sBp += vp; } \
      else if (vp < f1P) { u32 ix = atomicAdd(&nP, 1u); if (ix < LCAP) capP[ix] = vp; } \
      sTy += vy; \
      if (vy < f0Y) { nBy++; sBy += vy; } \
      else if (vy < f1Y) { u32 ix = atomicAdd(&nY, 1u); if (ix < LCAP) capY[ix] = vy; } }

  const int S = BPI * 256;
  int i = blk * 256 + threadIdx.x;
  for (; i + S < HW4; i += 2 * S) {
    float4 pa = pb[i], pc = pb[i + S];
    float4 ya = yb[i], yc = yb[i + S];
    int4 ma = mb[i], mc = mb[i + S];
    uchar4 wa, wc;
    wa.x = ma.x ? 1 : 0; wa.y = ma.y ? 1 : 0; wa.z = ma.z ? 1 : 0; wa.w = ma.w ? 1 : 0;
    wc.x = mc.x ? 1 : 0; wc.y = mc.y ? 1 : 0; wc.z = mc.z ? 1 : 0; wc.w = mc.w ? 1 : 0;
    mo[i] = wa; mo[i + S] = wc;
    PEL(wa.x, pa.x, ya.x) PEL(wa.y, pa.y, ya.y) PEL(wa.z, pa.z, ya.z) PEL(wa.w, pa.w, ya.w)
    PEL(wc.x, pc.x, yc.x) PEL(wc.y, pc.y, yc.y) PEL(wc.z, pc.z, yc.z) PEL(wc.w, pc.w, yc.w)
  }
  if (i < HW4) {
    float4 pv = pb[i]; float4 yv = yb[i]; int4 mv = mb[i];
    uchar4 mw; mw.x = mv.x ? 1 : 0; mw.y = mv.y ? 1 : 0; mw.z = mv.z ? 1 : 0; mw.w = mv.w ? 1 : 0;
    mo[i] = mw;
    PEL(mw.x, pv.x, yv.x) PEL(mw.y, pv.y, yv.y) PEL(mw.z, pv.z, yv.z) PEL(mw.w, pv.w, yv.w)
  }
#undef PEL

  __syncthreads();
  if (threadIdx.x == 0) {
    u32 np = nP, ny = nY;
    u32 addP = (np > (u32)LCAP) ? (u32)(CAP + 1) : np;
    u32 addY = (ny > (u32)LCAP) ? (u32)(CAP + 1) : ny;
    baseP = atomicAdd(&ccnt[img * 2 + 0], addP);
    baseY = atomicAdd(&ccnt[img * 2 + 1], addY);
  }
  __syncthreads();
  {
    u32 np = min(nP, (u32)LCAP), ny = min(nY, (u32)LCAP);
    float* cp = cand + (size_t)(img * 2 + 0) * CAP;
    float* cy = cand + (size_t)(img * 2 + 1) * CAP;
    for (u32 k = threadIdx.x; k < np; k += 256) { u32 g = baseP + k; if (g < CAP) cp[g] = capP[k]; }
    for (u32 k = threadIdx.x; k < ny; k += 256) { u32 g = baseY + k; if (g < CAP) cy[g] = capY[k]; }
  }
  double v0 = (double)sTp, v1 = (double)sBp, v2 = (double)sTy, v3 = (double)sBy;
  double v4 = (double)lc, v5 = (double)nBp, v6 = (double)nBy;
  for (int o = 32; o; o >>= 1) {
    v0 += __shfl_down(v0, o, 64); v1 += __shfl_down(v1, o, 64);
    v2 += __shfl_down(v2, o, 64); v3 += __shfl_down(v3, o, 64);
    v4 += __shfl_down(v4, o, 64); v5 += __shfl_down(v5, o, 64);
    v6 += __shfl_down(v6, o, 64);
  }
  __shared__ double sh[7][4];
  int lane = threadIdx.x & 63, wv = threadIdx.x >> 6;
  if (lane == 0) { sh[0][wv]=v0; sh[1][wv]=v1; sh[2][wv]=v2; sh[3][wv]=v3; sh[4][wv]=v4; sh[5][wv]=v5; sh[6][wv]=v6; }
  __syncthreads();
  if (threadIdx.x == 0) {
    double a[7];
    for (int k = 0; k < 7; k++) a[k] = sh[k][0] + sh[k][1] + sh[k][2] + sh[k][3];
    atomicAdd(&Stot[img * 2 + 0], a[0]);
    atomicAdd(&Sbl [img * 2 + 0], a[1]);
    atomicAdd(&Stot[img * 2 + 1], a[2]);
    atomicAdd(&Sbl [img * 2 + 1], a[3]);
    atomicAdd(&cnt[img], (u32)a[4]);
    atomicAdd(&Nbl[img * 2 + 0], (u32)a[5]);
    atomicAdd(&Nbl[img * 2 + 1], (u32)a[6]);
  }
}

// ---------- exact median + MAD (fast path; integrated exact fallback) ----------
__global__ __launch_bounds__(256) void k_med2(const float* __restrict__ cand,
    const u32* __restrict__ ccnt, const u32* __restrict__ cnt,
    const u32* __restrict__ Nbl, const double* __restrict__ Stot,
    const double* __restrict__ Sbl, const u32* __restrict__ selw,
    const float* __restrict__ pf, const float* __restrict__ yf,
    const u8* __restrict__ mu8, float* __restrict__ med, float* __restrict__ sci)
{
  int t = blockIdx.x, img = t >> 1;
  u32 c = cnt[img];
  if (c == 0) {
    if (threadIdx.x == 0) { med[t] = 0.f; sci[t] = 1e8f; }
    return;
  }
  u32 ntot = ccnt[t];
  u32 target0 = (c - 1) >> 1;
  u32 nb = Nbl[t];
  bool valid = (ntot <= (u32)CAP) && (target0 >= nb) && ((target0 - nb) < ntot);
  __shared__ u32 h[2048];
  __shared__ u32 sBin, sRank;
  if (threadIdx.x == 0) { sBin = 0; sRank = 0; }
  int lane = threadIdx.x & 63, wv = threadIdx.x >> 6;
  __shared__ double sh2[2][4];

  if (valid) {
    u32 n = ntot;
    const float* cd = cand + (size_t)t * CAP;
    u32 curLo = selw[2 * t + 0];
    u64 curR = (u64)selw[2 * t + 1] - (u64)curLo;
    u32 tgt = target0 - nb;
    for (int pass = 0; pass < 3; pass++) {
      int s = 0;
      while (((curR - 1) >> s) >= 2048) s++;
      for (int i = threadIdx.x; i < 2048; i += 256) h[i] = 0;
      __syncthreads();
      for (u32 j = threadIdx.x; j < n; j += 256) {
        u32 k = f2key(cd[j]);
        if (k >= curLo && (u64)(k - curLo) < curR)
          atomicAdd(&h[(k - curLo) >> s], 1u);
      }
      __syncthreads();
      blk_rankfind(h, tgt, true, &sBin, &sRank);
      curLo = curLo + (sBin << s);
      curR = (u64)1 << s;
      tgt = sRank;
      if (s == 0) break;
    }
    float mv = key2f(curLo);
    u32 nlt2 = 0; float slt2 = 0.f;
    for (u32 j = threadIdx.x; j < n; j += 256) {
      float v = cd[j];
      if (v < mv) { nlt2++; slt2 += v; }
    }
    double v0 = (double)nlt2, v1 = (double)slt2;
    for (int o = 32; o; o >>= 1) { v0 += __shfl_down(v0, o, 64); v1 += __shfl_down(v1, o, 64); }
    if (lane == 0) { sh2[0][wv] = v0; sh2[1][wv] = v1; }
    __syncthreads();
    if (threadIdx.x == 0) {
      double nl = (double)nb + sh2[0][0] + sh2[0][1] + sh2[0][2] + sh2[0][3];
      double sl = Sbl[t] + sh2[1][0] + sh2[1][1] + sh2[1][2] + sh2[1][3];
      double md = (double)mv;
      double mad = Stot[t] + 2.0 * md * nl - 2.0 * sl - md * (double)c;
      double sc = mad / (double)c + 1e-8;
      med[t] = mv; sci[t] = (float)(1.0 / sc);
    }
  } else {
    const float* src = ((t & 1) ? yf : pf) + (size_t)img * HW;
    const u8* mk = mu8 + (size_t)img * HW;
    u32 curLo = 0; u64 curR = (u64)1 << 32; u32 tgt = target0;
    for (int pass = 0; pass < 4; pass++) {
      int s = 0;
      while (((curR - 1) >> s) >= 2048) s++;
      for (int i = threadIdx.x; i < 2048; i += 256) h[i] = 0;
      __syncthreads();
      for (u32 j = threadIdx.x; j < (u32)HW; j += 256) {
        if (mk[j]) {
          u32 k = f2key(src[j]);
          if (k >= curLo && (u64)(k - curLo) < curR)
            atomicAdd(&h[(k - curLo) >> s], 1u);
        }
      }
      __syncthreads();
      blk_rankfind(h, tgt, true, &sBin, &sRank);
      curLo = curLo + (sBin << s);
      curR = (u64)1 << s;
      tgt = sRank;
      if (s == 0) break;
    }
    float mv = key2f(curLo);
    double nl = 0.0, sl = 0.0;
    for (u32 j = threadIdx.x; j < (u32)HW; j += 256) {
      if (mk[j]) {
        float v = src[j];
        if (v < mv) { nl += 1.0; sl += (double)v; }
      }
    }
    for (int o = 32; o; o >>= 1) { nl += __shfl_down(nl, o, 64); sl += __shfl_down(sl, o, 64); }
    if (lane == 0) { sh2[0][wv] = nl; sh2[1][wv] = sl; }
    __syncthreads();
    if (threadIdx.x == 0) {
      double nlT = sh2[0][0] + sh2[0][1] + sh2[0][2] + sh2[0][3];
      double slT = sh2[1][0] + sh2[1][1] + sh2[1][2] + sh2[1][3];
      double md = (double)mv;
      double mad = Stot[t] + 2.0 * md * nlT - 2.0 * slT - md * (double)c;
      double sc = mad / (double)c + 1e-8;
      med[t] = mv; sci[t] = (float)(1.0 / sc);
    }
  }
}

// ---------- fused: D in registers + rho + scale-0 grad + pool0 (padded P1 write) ----------
__global__ __launch_bounds__(320) void k_fuse0(const float* __restrict__ p,
    const float* __restrict__ y, const u8* __restrict__ mu,
    const float* __restrict__ medv, const float* __restrict__ sciv,
    float* __restrict__ P1, u8* __restrict__ M1,
    double* __restrict__ rho, double* __restrict__ gI)
{
  int img = blockIdx.x / NB0, band = blockIdx.x % NB0;
  float mp = medv[img * 2 + 0], my = medv[img * 2 + 1];
  float ap = sciv[img * 2 + 0], ay = sciv[img * 2 + 1];
  const float* pb = p + (size_t)img * HW;
  const float* yb = y + (size_t)img * HW;
  const u8*   mb = mu + (size_t)img * HW;
  int ra = band * 16;
  int rb = min(ra + 16, H0);
  int rend = (rb < H0) ? rb + 1 : H0;
  int oc = threadIdx.x;
  bool act = oc < 259;
  int cc = act ? 2 * oc : 516;
  bool vn = act && (2 * oc + 2 < W0);
  int lane = threadIdx.x & 63;
  bool edge = (lane == 63);
  float gx = 0.f, gy = 0.f, rr = 0.f;
  int cx = 0, cy = 0;
  float pd0 = 0.f, pd1 = 0.f; u8 pm0 = 0, pm1 = 0;
  float2 pv0, yv0, pv1, yv1;
  uchar2 mv0, mv1;
  {
    size_t a0 = (size_t)ra * W0 + cc;
    pv0 = *(const float2*)(pb + a0); yv0 = *(const float2*)(yb + a0); mv0 = *(const uchar2*)(mb + a0);
    if (ra + 1 < rend) {
      size_t a1 = a0 + W0;
      pv1 = *(const float2*)(pb + a1); yv1 = *(const float2*)(yb + a1); mv1 = *(const uchar2*)(mb + a1);
    } else { pv1 = pv0; yv1 = yv0; mv1 = mv0; }
  }
  for (int r = ra; r < rend; ++r) {
    float2 pv2 = pv1, yv2 = yv1; uchar2 mv2 = mv1;
    if (r + 2 < rend) {
      size_t a2 = (size_t)(r + 2) * W0 + cc;
      pv2 = *(const float2*)(pb + a2); yv2 = *(const float2*)(yb + a2); mv2 = *(const uchar2*)(mb + a2);
    }
    bool core = r < rb;
    float d0 = (pv0.x - mp) * ap - (yv0.x - my) * ay;
    float d1 = (pv0.y - mp) * ap - (yv0.y - my) * ay;
    u8 m0 = mv0.x, m1 = mv0.y;
    float dn = __shfl_down(d0, 1, 64);
    int mn = __shfl_down((int)m0, 1, 64);
    if (vn && edge) {
      size_t a = (size_t)r * W0 + (size_t)cc + 2;
      float pnb = pb[a], ynb = yb[a];
      dn = (pnb - mp) * ap - (ynb - my) * ay;
      mn = mb[a];
    }
    if (act) {
      float f0 = (float)m0, f1 = (float)m1;
      if (core) {
        gx += f0 * f1 * fabsf(d1 - d0); cx += (int)(m0 & m1);
        if (vn) { float fn = (float)mn; gx += f1 * fn * fabsf(dn - d1); cx += (m1 && mn) ? 1 : 0; }
        rr += f0 * fabsf(d0) + f1 * fabsf(d1);
      }
      if (r > ra) {
        gy += f0 * (float)pm0 * fabsf(d0 - pd0); cy += (int)(m0 & pm0);
        gy += f1 * (float)pm1 * fabsf(d1 - pd1); cy += (int)(m1 & pm1);
      }
      if (core && (r & 1)) {
        size_t o = (size_t)img * N1P + (size_t)(r >> 1) * W1S + oc;
        P1[o] = 0.25f * (pd0 + pd1 + d0 + d1);
        M1[o] = (u8)((pm0 | pm1 | m0 | m1) ? 1 : 0);
      }
    }
    pd0 = d0; pd1 = d1; pm0 = m0; pm1 = m1;
    pv0 = pv1; yv0 = yv1; mv0 = mv1;
    pv1 = pv2; yv1 = yv2; mv1 = mv2;
  }
  double v0 = (double)gx, v1 = (double)cx, v2 = (double)gy, v3 = (double)cy, v4 = (double)rr;
  for (int o = 32; o; o >>= 1) {
    v0 += __shfl_down(v0, o, 64); v1 += __shfl_down(v1, o, 64);
    v2 += __shfl_down(v2, o, 64); v3 += __shfl_down(v3, o, 64);
    v4 += __shfl_down(v4, o, 64);
  }
  __shared__ double sh[5][5];
  int wv = threadIdx.x >> 6;
  if (lane == 0) { sh[0][wv] = v0; sh[1][wv] = v1; sh[2][wv] = v2; sh[3][wv] = v3; sh[4][wv] = v4; }
  __syncthreads();
  if (threadIdx.x == 0) {
    double a0 = 0, a1 = 0, a2 = 0, a3 = 0, a4 = 0;
    for (int w = 0; w < 5; w++) { a0 += sh[0][w]; a1 += sh[1][w]; a2 += sh[2][w]; a3 += sh[3][w]; a4 += sh[4][w]; }
    atomicAdd(&gI[img * 4 + 0], a0);
    atomicAdd(&gI[img * 4 + 1], a1);
    atomicAdd(&gI[img * 4 + 2], a2);
    atomicAdd(&gI[img * 4 + 3], a3);
    atomicAdd(&rho[img], a4);
  }
}

// ---------- grad+pool scale 1 (259 -> 129), padded strides, float2 + shfl ----------
__global__ void k_gp(const float* __restrict__ Pin,
    const u8* __restrict__ Min, float* __restrict__ Pout, u8* __restrict__ Mout,
    double* __restrict__ gI)
{
  const int WinL = 259, Hin = 259, WoutL = 129, Hout = 129, nb = 17;
  int img = blockIdx.x / nb, band = blockIdx.x % nb;
  const float* pb = Pin + (size_t)img * N1P;
  const u8* mb = Min + (size_t)img * N1P;
  int poolEnd = 2 * Hout;                         // 258
  int ra = band * 16;
  int rb = min(ra + 16, poolEnd);
  int rbx = (band == nb - 1) ? Hin : rb;
  int rend = (rbx < Hin) ? rbx + 1 : Hin;
  float gx = 0.f, gy = 0.f;
  int cx = 0, cy = 0;
  int oc = threadIdx.x;
  bool act = oc < WoutL;
  int lane = threadIdx.x & 63;
  int c0 = act ? 2 * oc : 0;
  int cn = c0 + 2;
  bool vn = act && (cn < WinL);
  bool gyn = vn && (cn >= 2 * WoutL);             // oc == 128 extra column
  bool direct = vn && ((lane == 63) || (oc == 128));
  float pd0 = 0.f, pd1 = 0.f, pdn = 0.f;
  u8 pm0 = 0, pm1 = 0, pmn = 0;
  for (int r = ra; r < rend; ++r) {
    int base = r * W1S;
    float2 dv = act ? *(const float2*)(pb + base + c0) : make_float2(0.f, 0.f);
    uchar2 mv = act ? *(const uchar2*)(mb + base + c0) : make_uchar2(0, 0);
    float d0 = dv.x, d1 = dv.y;
    u8 m0 = mv.x, m1 = mv.y;
    float dn = __shfl_down(d0, 1, 64);
    int mni = __shfl_down((int)m0, 1, 64);
    if (direct) { dn = pb[base + cn]; mni = mb[base + cn]; }
    u8 mn = (u8)mni;
    bool core = r < rbx;
    if (act) {
      if (core) {
        if (m0 & m1) { gx += fabsf(d1 - d0); cx++; }
        if (vn && (m1 & mn)) { gx += fabsf(dn - d1); cx++; }
      }
      if (r > ra) {
        if (m0 & pm0) { gy += fabsf(d0 - pd0); cy++; }
        if (m1 & pm1) { gy += fabsf(d1 - pd1); cy++; }
        if (gyn && (mn & pmn)) { gy += fabsf(dn - pdn); cy++; }
      }
      if (core && (r & 1) && r < poolEnd) {
        size_t o = (size_t)img * N2P + (size_t)(r >> 1) * W2S + oc;
        Pout[o] = 0.25f * (pd0 + pd1 + d0 + d1);
        Mout[o] = (u8)((pm0 | pm1 | m0 | m1) ? 1 : 0);
      }
    }
    pd0 = d0; pd1 = d1; pdn = dn; pm0 = m0; pm1 = m1; pmn = mn;
  }
  double v0 = (double)gx, v1 = (double)cx, v2 = (double)gy, v3 = (double)cy;
  for (int o = 32; o; o >>= 1) {
    v0 += __shfl_down(v0, o, 64); v1 += __shfl_down(v1, o, 64);
    v2 += __shfl_down(v2, o, 64); v3 += __shfl_down(v3, o, 64);
  }
  __shared__ double sh[4][3];
  int wv = threadIdx.x >> 6;
  if (lane == 0) { sh[0][wv] = v0; sh[1][wv] = v1; sh[2][wv] = v2; sh[3][wv] = v3; }
  __syncthreads();
  if (threadIdx.x == 0) {
    double a0 = sh[0][0] + sh[0][1] + sh[0][2];
    double a1 = sh[1][0] + sh[1][1] + sh[1][2];
    double a2 = sh[2][0] + sh[2][1] + sh[2][2];
    double a3 = sh[3][0] + sh[3][1] + sh[3][2];
    atomicAdd(&gI[img * 4 + 0], a0);
    atomicAdd(&gI[img * 4 + 1], a1);
    atomicAdd(&gI[img * 4 + 2], a2);
    atomicAdd(&gI[img * 4 + 3], a3);
  }
}

// ---------- last level: grad2 (129x129) + in-register pool -> grad3 (64x64) ----------
__global__ __launch_bounds__(64) void k_gp_last(const float* __restrict__ Pin,
    const u8* __restrict__ Min, double* __restrict__ gI2v, double* __restrict__ gI3v)
{
  const int WinL = 129, Hin = 129, Wout = 64, nb = 8;
  int img = blockIdx.x / nb, band = blockIdx.x % nb;
  const float* pb = Pin + (size_t)img * N2P;
  const u8* mb = Min + (size_t)img * N2P;
  int ra = band * 16;
  int rb = min(ra + 16, 128);
  int rbx = (band == nb - 1) ? Hin : rb;
  int rend2 = (band < nb - 1) ? (ra + 18) : Hin;
  float gx = 0.f, gy = 0.f; int cx = 0, cy = 0;
  float ogx = 0.f, ogy = 0.f; int ocx = 0, ocy = 0;
  int oc = threadIdx.x;                      // 0..63
  int c0 = 2 * oc, cn = c0 + 2;
  bool vn = cn < WinL;
  bool gyn = vn && (cn >= 2 * Wout);         // oc == 63
  float pd0 = 0.f, pd1 = 0.f, pdn = 0.f;
  u8 pm0 = 0, pm1 = 0, pmn = 0;
  float ppo = 0.f; int pmo = 0; bool havePrev = false;
  for (int r = ra; r < rend2; ++r) {
    int base = r * W2S;
    float2 dv = *(const float2*)(pb + base + c0);
    uchar2 mv = *(const uchar2*)(mb + base + c0);
    float d0 = dv.x, d1 = dv.y;
    u8 m0 = mv.x, m1 = mv.y;
    float dn = __shfl_down(d0, 1, 64);
    int mni = __shfl_down((int)m0, 1, 64);
    if (vn && oc == 63) { dn = pb[base + cn]; mni = mb[base + cn]; }
    u8 mn = (u8)mni;
    if (r < rbx) {
      if (m0 & m1) { gx += fabsf(d1 - d0); cx++; }
      if (vn && (m1 & mn)) { gx += fabsf(dn - d1); cx++; }
    }
    if (r > ra && r <= rb) {
      if (m0 & pm0) { gy += fabsf(d0 - pd0); cy++; }
      if (m1 & pm1) { gy += fabsf(d1 - pd1); cy++; }
      if (gyn && (mn & pmn)) { gy += fabsf(dn - pdn); cy++; }
    }
    if (r & 1) {
      bool owned = r < rb;
      bool halo = (r == rb + 1);
      if (owned || halo) {
        float po = 0.25f * (pd0 + pd1 + d0 + d1);
        int mo = (pm0 | pm1 | m0 | m1) ? 1 : 0;
        float pon = __shfl_down(po, 1, 64);
        int mon = __shfl_down(mo, 1, 64);
        if (owned && oc < 63 && mo && mon) { ogx += fabsf(pon - po); ocx++; }
        if (havePrev && mo && pmo) { ogy += fabsf(po - ppo); ocy++; }
        ppo = po; pmo = mo; havePrev = true;
      }
    }
    pd0 = d0; pd1 = d1; pdn = dn; pm0 = m0; pm1 = m1; pmn = mn;
  }
  double v[8] = {(double)gx, (double)cx, (double)gy, (double)cy,
                 (double)ogx, (double)ocx, (double)ogy, (double)ocy};
  for (int o = 32; o; o >>= 1)
    for (int k = 0; k < 8; k++) v[k] += __shfl_down(v[k], o, 64);
  if (threadIdx.x == 0) {
    atomicAdd(&gI2v[img * 4 + 0], v[0]);
    atomicAdd(&gI2v[img * 4 + 1], v[1]);
    atomicAdd(&gI2v[img * 4 + 2], v[2]);
    atomicAdd(&gI2v[img * 4 + 3], v[3]);
    atomicAdd(&gI3v[img * 4 + 0], v[4]);
    atomicAdd(&gI3v[img * 4 + 1], v[5]);
    atomicAdd(&gI3v[img * 4 + 2], v[6]);
    atomicAdd(&gI3v[img * 4 + 3], v[7]);
  }
}

// ---------- finalize ----------
__global__ void k_final(const double* __restrict__ rho, const u32* __restrict__ cnt,
    const double* __restrict__ gI0, const double* __restrict__ gI1,
    const double* __restrict__ gI2, const double* __restrict__ gI3,
    float* __restrict__ out)
{
  int i = threadIdx.x;
  double v[17];
  double c = cnt[i] ? (double)cnt[i] : 1.0;
  v[0] = rho[i] / c;
  for (int j = 0; j < 4; j++) {
    v[1 + 0 * 4 + j] = gI0[i * 4 + j];
    v[1 + 1 * 4 + j] = gI1[i * 4 + j];
    v[1 + 2 * 4 + j] = gI2[i * 4 + j];
    v[1 + 3 * 4 + j] = gI3[i * 4 + j];
  }
  for (int o = 32; o; o >>= 1)
    for (int k = 0; k < 17; k++) v[k] += __shfl_down(v[k], o, 64);
  if (i == 0) {
    double ssi = v[0] / (double)NIMG;
    double g = 0.0;
    for (int s = 0; s < 4; s++) {
      double gxs = v[1 + s * 4 + 0], cxs = v[1 + s * 4 + 1];
      double gys = v[1 + s * 4 + 2], cys = v[1 + s * 4 + 3];
      g += gxs / (cxs > 1.0 ? cxs : 1.0);
      g += gys / (cys > 1.0 ? cys : 1.0);
    }
    g /= 4.0;
    out[0] = (float)(ssi + 0.5 * g);
  }
}

extern "C" void kernel_launch(void* const* d_in, const int* in_sizes, int n_in,
                              void* d_out, int out_size, void* d_ws, size_t ws_size,
                              hipStream_t stream) {
  (void)in_sizes; (void)n_in; (void)out_size; (void)ws_size;
  const float4* p4 = (const float4*)d_in[0];
  const float4* y4 = (const float4*)d_in[1];
  const int4* m4 = (const int4*)d_in[2];
  const float* pf = (const float*)d_in[0];
  const float* yf = (const float*)d_in[1];
  u8* ws = (u8*)d_ws;

  u32*    cnt  = (u32*)(ws + OFF_CNT);
  u32*    ccnt = (u32*)(ws + OFF_CCNT);
  u32*    Nbl  = (u32*)(ws + OFF_NBL);
  double* rho  = (double*)(ws + OFF_RHO);
  double* Stot = (double*)(ws + OFF_STOT);
  double* Sbl  = (double*)(ws + OFF_SBL);
  double* gI0  = (double*)(ws + OFF_GI0);
  double* gI1  = (double*)(ws + OFF_GI1);
  double* gI2  = (double*)(ws + OFF_GI2);
  double* gI3  = (double*)(ws + OFF_GI3);
  float*  med  = (float*)(ws + OFF_MED);
  float*  sci  = (float*)(ws + OFF_SCI);
  u32*    selw = (u32*)(ws + OFF_SELW);
  float*  swf  = (float*)(ws + OFF_SWF);
  float*  cand = (float*)(ws + OFF_CAND);
  u8*     mu8  = (u8*)(ws + OFF_MU8);
  float*  P1   = (float*)(ws + OFF_P1);
  u8*     M1   = (u8*)(ws + OFF_M1);
  float*  P2   = (float*)(ws + OFF_P2);
  u8*     M2   = (u8*)(ws + OFF_M2);

  k_sample<<<128, 256, 0, stream>>>(pf, yf, selw, swf, (u32*)ws);
  k_scan0<<<NIMG * BPI, 256, 0, stream>>>(p4, y4, m4, (uchar4*)mu8, swf, cand, ccnt, cnt, Stot, Nbl, Sbl);
  k_med2<<<128, 256, 0, stream>>>(cand, ccnt, cnt, Nbl, Stot, Sbl, selw, pf, yf, mu8, med, sci);
  k_fuse0<<<NIMG * NB0, 320, 0, stream>>>(pf, yf, mu8, med, sci, P1, M1, rho, gI0);
  k_gp<<<NIMG * 17, 192, 0, stream>>>(P1, M1, P2, M2, gI1);
  k_gp_last<<<NIMG * 8, 64, 0, stream>>>(P2, M2, gI2, gI3);
  k_final<<<1, 64, 0, stream>>>(rho, cnt, gI0, gI1, gI2, gI3, (float*)d_out);
}

// Round 10
// 319.917 us; speedup vs baseline: 1.3179x; 1.1495x over previous
//
#include <hip/hip_runtime.h>
#include <stdint.h>

typedef unsigned int u32;
typedef unsigned long long u64;
typedef unsigned char u8;

#define NIMG 64
#define W0   518
#define H0   518
#define HW   268324
#define HW4  67081
#define BPI  32
#define NB0  33
#define CAP 32768
#define LCAP 1024

// padded pyramid strides (even => aligned float2 loads)
#define W1S  260
#define H1   259
#define N1P  (W1S * H1)      // 67340
#define W2S  130
#define H2   129
#define N2P  (W2S * H2)      // 16770

// ---- workspace layout ----
#define OFF_CNT   0ULL        // u32[64]
#define OFF_CCNT  256ULL      // u32[128]
#define OFF_NBL   768ULL      // u32[128]
#define OFF_RHO   1280ULL     // double[64]
#define OFF_STOT  1792ULL     // double[128]
#define OFF_SBL   2816ULL     // double[128]
#define OFF_GI0   3840ULL     // double[256]
#define OFF_GI1   5888ULL
#define OFF_GI2   7936ULL
#define OFF_GI3   9984ULL
#define ZERO_END  12288ULL    // zero 3072 u32
#define OFF_MED   12288ULL    // float[128]
#define OFF_SCI   12800ULL    // float[128]
#define OFF_SELW  13312ULL    // u32[256]
#define OFF_SWF   14336ULL    // float[256]
#define OFF_CAND  15360ULL                    // float[128][CAP]
#define OFF_MU8   (OFF_CAND + 16777216ULL)    // u8[64*HW]
#define OFF_P1    (OFF_MU8 + 17172736ULL)     // float[64*N1P]
#define OFF_M1    (OFF_P1 + 17239040ULL)      // u8[64*N1P]
#define OFF_P2    (OFF_M1 + 4309760ULL)       // float[64*N2P]
#define OFF_M2    (OFF_P2 + 4293120ULL)       // u8[64*N2P]

__device__ __forceinline__ u32 f2key(float f) {
  u32 u = __float_as_uint(f);
  return (u & 0x80000000u) ? ~u : (u | 0x80000000u);
}
__device__ __forceinline__ float key2f(u32 k) {
  u32 u = (k & 0x80000000u) ? (k & 0x7fffffffu) : ~k;
  return __uint_as_float(u);
}

// block rank-find over LDS hist h[2048]; NT = block size (256 or 1024).
template <int NT>
__device__ void rankfindT(u32* h, u32 target, bool enable, u32* outBin, u32* outRank)
{
  const int PER = 2048 / NT;
  const int NW = NT / 64;
  int b0 = threadIdx.x * PER;
  u32 s = 0;
  for (int j = 0; j < PER; j++) s += h[b0 + j];
  u32 x = s;
  int lane = threadIdx.x & 63;
  for (int o = 1; o < 64; o <<= 1) {
    u32 v = __shfl_up(x, o, 64);
    if (lane >= o) x += v;
  }
  __shared__ u32 wsum[NW];
  int wv = threadIdx.x >> 6;
  if (lane == 63) wsum[wv] = x;
  __syncthreads();
  u32 woff = 0;
  for (int w = 0; w < wv; w++) woff += wsum[w];
  u32 cum = woff + x - s;
  for (int j = 0; j < PER; j++) {
    u32 v = h[b0 + j];
    if (enable && target >= cum && target < cum + v) { *outBin = (u32)(b0 + j); *outRank = target - cum; }
    cum += v;
  }
  __syncthreads();
}

// ---------- sample window + zero accumulators ----------
__global__ __launch_bounds__(256) void k_sample(const float* __restrict__ p,
    const float* __restrict__ y, u32* __restrict__ selw, float* __restrict__ swf,
    u32* __restrict__ zbase)
{
  int t = blockIdx.x, img = t >> 1;
  if (t == 0) {
    for (int i = threadIdx.x; i < 3072; i += 256) zbase[i] = 0;
  }
  const float* src = ((t & 1) ? y : p) + (size_t)img * HW;
  __shared__ u32 h[2048];
  __shared__ u32 bLo, rT, bHi;
  if (threadIdx.x == 0) { bLo = 0; bHi = 2047; }
  for (int i = threadIdx.x; i < 2048; i += 256) h[i] = 0;
  __syncthreads();
  for (int j = 0; j < 16; j++) {
    int s = threadIdx.x * 16 + j;
    float v = src[s * 65 + 32];
    atomicAdd(&h[f2key(v) >> 21], 1u);
  }
  __syncthreads();
  rankfindT<256>(h, 1919u, true, &bLo, &rT);
  rankfindT<256>(h, 2175u, true, &bHi, &rT);
  if (threadIdx.x == 0) {
    u32 k0 = bLo << 21;
    u32 k1 = (bHi >= 2047u) ? 0xFFFFFFFFu : ((bHi + 1u) << 21);
    selw[2 * t + 0] = k0;
    selw[2 * t + 1] = k1;
    float f0 = (k0 <= 0x007FFFFFu) ? __uint_as_float(0xFF800000u) : key2f(k0);
    float f1 = (k1 >= 0xFF800000u) ? __uint_as_float(0x7F800000u) : key2f(k1);
    swf[2 * t + 0] = f0;
    swf[2 * t + 1] = f1;
  }
}

// ---------- single full scan: mask write, cnt, Stot, below stats, capture ----------
__global__ __launch_bounds__(256) void k_scan0(const float4* __restrict__ p,
    const float4* __restrict__ y, const int4* __restrict__ m,
    uchar4* __restrict__ mu4, const float* __restrict__ swf,
    float* __restrict__ cand, u32* __restrict__ ccnt, u32* __restrict__ cnt,
    double* __restrict__ Stot, u32* __restrict__ Nbl, double* __restrict__ Sbl)
{
  __shared__ float capP[LCAP], capY[LCAP];
  __shared__ u32 nP, nY, baseP, baseY;
  if (threadIdx.x == 0) { nP = 0; nY = 0; }
  __syncthreads();
  int img = blockIdx.x / BPI, blk = blockIdx.x % BPI;
  float f0P = swf[img * 4 + 0], f1P = swf[img * 4 + 1];
  float f0Y = swf[img * 4 + 2], f1Y = swf[img * 4 + 3];
  const float4* pb = p + (size_t)img * HW4;
  const float4* yb = y + (size_t)img * HW4;
  const int4* mb = m + (size_t)img * HW4;
  uchar4* mo = mu4 + (size_t)img * HW4;
  int lc = 0, nBp = 0, nBy = 0;
  float sTp = 0.f, sBp = 0.f, sTy = 0.f, sBy = 0.f;

#define PEL(mm, vp, vy) if (mm) { lc++; \
      sTp += vp; \
      if (vp < f0P) { nBp++; sBp += vp; } \
      else if (vp < f1P) { u32 ix = atomicAdd(&nP, 1u); if (ix < LCAP) capP[ix] = vp; } \
      sTy += vy; \
      if (vy < f0Y) { nBy++; sBy += vy; } \
      else if (vy < f1Y) { u32 ix = atomicAdd(&nY, 1u); if (ix < LCAP) capY[ix] = vy; } }

  const int S = BPI * 256;
  int i = blk * 256 + threadIdx.x;
  for (; i + S < HW4; i += 2 * S) {
    float4 pa = pb[i], pc = pb[i + S];
    float4 ya = yb[i], yc = yb[i + S];
    int4 ma = mb[i], mc = mb[i + S];
    uchar4 wa, wc;
    wa.x = ma.x ? 1 : 0; wa.y = ma.y ? 1 : 0; wa.z = ma.z ? 1 : 0; wa.w = ma.w ? 1 : 0;
    wc.x = mc.x ? 1 : 0; wc.y = mc.y ? 1 : 0; wc.z = mc.z ? 1 : 0; wc.w = mc.w ? 1 : 0;
    mo[i] = wa; mo[i + S] = wc;
    PEL(wa.x, pa.x, ya.x) PEL(wa.y, pa.y, ya.y) PEL(wa.z, pa.z, ya.z) PEL(wa.w, pa.w, ya.w)
    PEL(wc.x, pc.x, yc.x) PEL(wc.y, pc.y, yc.y) PEL(wc.z, pc.z, yc.z) PEL(wc.w, pc.w, yc.w)
  }
  if (i < HW4) {
    float4 pv = pb[i]; float4 yv = yb[i]; int4 mv = mb[i];
    uchar4 mw; mw.x = mv.x ? 1 : 0; mw.y = mv.y ? 1 : 0; mw.z = mv.z ? 1 : 0; mw.w = mv.w ? 1 : 0;
    mo[i] = mw;
    PEL(mw.x, pv.x, yv.x) PEL(mw.y, pv.y, yv.y) PEL(mw.z, pv.z, yv.z) PEL(mw.w, pv.w, yv.w)
  }
#undef PEL

  __syncthreads();
  if (threadIdx.x == 0) {
    u32 np = nP, ny = nY;
    u32 addP = (np > (u32)LCAP) ? (u32)(CAP + 1) : np;
    u32 addY = (ny > (u32)LCAP) ? (u32)(CAP + 1) : ny;
    baseP = atomicAdd(&ccnt[img * 2 + 0], addP);
    baseY = atomicAdd(&ccnt[img * 2 + 1], addY);
  }
  __syncthreads();
  {
    u32 np = min(nP, (u32)LCAP), ny = min(nY, (u32)LCAP);
    float* cp = cand + (size_t)(img * 2 + 0) * CAP;
    float* cy = cand + (size_t)(img * 2 + 1) * CAP;
    for (u32 k = threadIdx.x; k < np; k += 256) { u32 g = baseP + k; if (g < CAP) cp[g] = capP[k]; }
    for (u32 k = threadIdx.x; k < ny; k += 256) { u32 g = baseY + k; if (g < CAP) cy[g] = capY[k]; }
  }
  double v0 = (double)sTp, v1 = (double)sBp, v2 = (double)sTy, v3 = (double)sBy;
  double v4 = (double)lc, v5 = (double)nBp, v6 = (double)nBy;
  for (int o = 32; o; o >>= 1) {
    v0 += __shfl_down(v0, o, 64); v1 += __shfl_down(v1, o, 64);
    v2 += __shfl_down(v2, o, 64); v3 += __shfl_down(v3, o, 64);
    v4 += __shfl_down(v4, o, 64); v5 += __shfl_down(v5, o, 64);
    v6 += __shfl_down(v6, o, 64);
  }
  __shared__ double sh[7][4];
  int lane = threadIdx.x & 63, wv = threadIdx.x >> 6;
  if (lane == 0) { sh[0][wv]=v0; sh[1][wv]=v1; sh[2][wv]=v2; sh[3][wv]=v3; sh[4][wv]=v4; sh[5][wv]=v5; sh[6][wv]=v6; }
  __syncthreads();
  if (threadIdx.x == 0) {
    double a[7];
    for (int k = 0; k < 7; k++) a[k] = sh[k][0] + sh[k][1] + sh[k][2] + sh[k][3];
    atomicAdd(&Stot[img * 2 + 0], a[0]);
    atomicAdd(&Sbl [img * 2 + 0], a[1]);
    atomicAdd(&Stot[img * 2 + 1], a[2]);
    atomicAdd(&Sbl [img * 2 + 1], a[3]);
    atomicAdd(&cnt[img], (u32)a[4]);
    atomicAdd(&Nbl[img * 2 + 0], (u32)a[5]);
    atomicAdd(&Nbl[img * 2 + 1], (u32)a[6]);
  }
}

// ---------- exact median + MAD: 1024 threads, float4 candidate loads ----------
__global__ __launch_bounds__(1024) void k_med2(const float* __restrict__ cand,
    const u32* __restrict__ ccnt, const u32* __restrict__ cnt,
    const u32* __restrict__ Nbl, const double* __restrict__ Stot,
    const double* __restrict__ Sbl, const u32* __restrict__ selw,
    const float* __restrict__ pf, const float* __restrict__ yf,
    const u8* __restrict__ mu8, float* __restrict__ med, float* __restrict__ sci)
{
  int t = blockIdx.x, img = t >> 1;
  u32 c = cnt[img];
  if (c == 0) {
    if (threadIdx.x == 0) { med[t] = 0.f; sci[t] = 1e8f; }
    return;
  }
  u32 ntot = ccnt[t];
  u32 target0 = (c - 1) >> 1;
  u32 nb = Nbl[t];
  bool valid = (ntot <= (u32)CAP) && (target0 >= nb) && ((target0 - nb) < ntot);
  __shared__ u32 h[2048];
  __shared__ u32 sBin, sRank;
  if (threadIdx.x == 0) { sBin = 0; sRank = 0; }
  int lane = threadIdx.x & 63, wv = threadIdx.x >> 6;
  __shared__ double sh2[2][16];

  if (valid) {
    u32 n = ntot;
    const float* cd = cand + (size_t)t * CAP;
    const float4* cd4 = (const float4*)cd;
    u32 n4 = n >> 2;
    u32 curLo = selw[2 * t + 0];
    u64 curR = (u64)selw[2 * t + 1] - (u64)curLo;
    u32 tgt = target0 - nb;
    for (int pass = 0; pass < 3; pass++) {
      int s = 0;
      while (((curR - 1) >> s) >= 2048) s++;
      for (int i = threadIdx.x; i < 2048; i += 1024) h[i] = 0;
      __syncthreads();
#define HADD(vv) { u32 k = f2key(vv); \
        if (k >= curLo && (u64)(k - curLo) < curR) atomicAdd(&h[(k - curLo) >> s], 1u); }
      for (u32 j = threadIdx.x; j < n4; j += 1024) {
        float4 v = cd4[j];
        HADD(v.x) HADD(v.y) HADD(v.z) HADD(v.w)
      }
      for (u32 j = (n4 << 2) + threadIdx.x; j < n; j += 1024) HADD(cd[j])
#undef HADD
      __syncthreads();
      rankfindT<1024>(h, tgt, true, &sBin, &sRank);
      curLo = curLo + (sBin << s);
      curR = (u64)1 << s;
      tgt = sRank;
      if (s == 0) break;
    }
    float mv = key2f(curLo);
    u32 nlt2 = 0; float slt2 = 0.f;
    for (u32 j = threadIdx.x; j < n4; j += 1024) {
      float4 v = cd4[j];
      if (v.x < mv) { nlt2++; slt2 += v.x; }
      if (v.y < mv) { nlt2++; slt2 += v.y; }
      if (v.z < mv) { nlt2++; slt2 += v.z; }
      if (v.w < mv) { nlt2++; slt2 += v.w; }
    }
    for (u32 j = (n4 << 2) + threadIdx.x; j < n; j += 1024) {
      float v = cd[j];
      if (v < mv) { nlt2++; slt2 += v; }
    }
    double v0 = (double)nlt2, v1 = (double)slt2;
    for (int o = 32; o; o >>= 1) { v0 += __shfl_down(v0, o, 64); v1 += __shfl_down(v1, o, 64); }
    if (lane == 0) { sh2[0][wv] = v0; sh2[1][wv] = v1; }
    __syncthreads();
    if (threadIdx.x == 0) {
      double nl = (double)nb, sl = Sbl[t];
      for (int w = 0; w < 16; w++) { nl += sh2[0][w]; sl += sh2[1][w]; }
      double md = (double)mv;
      double mad = Stot[t] + 2.0 * md * nl - 2.0 * sl - md * (double)c;
      double sc = mad / (double)c + 1e-8;
      med[t] = mv; sci[t] = (float)(1.0 / sc);
    }
  } else {
    // exact fallback over the full array (rare)
    const float* src = ((t & 1) ? yf : pf) + (size_t)img * HW;
    const u8* mk = mu8 + (size_t)img * HW;
    u32 curLo = 0; u64 curR = (u64)1 << 32; u32 tgt = target0;
    for (int pass = 0; pass < 4; pass++) {
      int s = 0;
      while (((curR - 1) >> s) >= 2048) s++;
      for (int i = threadIdx.x; i < 2048; i += 1024) h[i] = 0;
      __syncthreads();
      for (u32 j = threadIdx.x; j < (u32)HW; j += 1024) {
        if (mk[j]) {
          u32 k = f2key(src[j]);
          if (k >= curLo && (u64)(k - curLo) < curR)
            atomicAdd(&h[(k - curLo) >> s], 1u);
        }
      }
      __syncthreads();
      rankfindT<1024>(h, tgt, true, &sBin, &sRank);
      curLo = curLo + (sBin << s);
      curR = (u64)1 << s;
      tgt = sRank;
      if (s == 0) break;
    }
    float mv = key2f(curLo);
    double nl = 0.0, sl = 0.0;
    for (u32 j = threadIdx.x; j < (u32)HW; j += 1024) {
      if (mk[j]) {
        float v = src[j];
        if (v < mv) { nl += 1.0; sl += (double)v; }
      }
    }
    for (int o = 32; o; o >>= 1) { nl += __shfl_down(nl, o, 64); sl += __shfl_down(sl, o, 64); }
    if (lane == 0) { sh2[0][wv] = nl; sh2[1][wv] = sl; }
    __syncthreads();
    if (threadIdx.x == 0) {
      double nlT = 0.0, slT = 0.0;
      for (int w = 0; w < 16; w++) { nlT += sh2[0][w]; slT += sh2[1][w]; }
      double md = (double)mv;
      double mad = Stot[t] + 2.0 * md * nlT - 2.0 * slT - md * (double)c;
      double sc = mad / (double)c + 1e-8;
      med[t] = mv; sci[t] = (float)(1.0 / sc);
    }
  }
}

// ---------- fused: D in registers + rho + scale-0 grad + pool0 (padded P1 write) ----------
__global__ __launch_bounds__(320) void k_fuse0(const float* __restrict__ p,
    const float* __restrict__ y, const u8* __restrict__ mu,
    const float* __restrict__ medv, const float* __restrict__ sciv,
    float* __restrict__ P1, u8* __restrict__ M1,
    double* __restrict__ rho, double* __restrict__ gI)
{
  int img = blockIdx.x / NB0, band = blockIdx.x % NB0;
  float mp = medv[img * 2 + 0], my = medv[img * 2 + 1];
  float ap = sciv[img * 2 + 0], ay = sciv[img * 2 + 1];
  const float* pb = p + (size_t)img * HW;
  const float* yb = y + (size_t)img * HW;
  const u8*   mb = mu + (size_t)img * HW;
  int ra = band * 16;
  int rb = min(ra + 16, H0);
  int rend = (rb < H0) ? rb + 1 : H0;
  int oc = threadIdx.x;
  bool act = oc < 259;
  int cc = act ? 2 * oc : 516;
  bool vn = act && (2 * oc + 2 < W0);
  int lane = threadIdx.x & 63;
  bool edge = (lane == 63);
  float gx = 0.f, gy = 0.f, rr = 0.f;
  int cx = 0, cy = 0;
  float pd0 = 0.f, pd1 = 0.f; u8 pm0 = 0, pm1 = 0;
  float2 pv0, yv0, pv1, yv1;
  uchar2 mv0, mv1;
  {
    size_t a0 = (size_t)ra * W0 + cc;
    pv0 = *(const float2*)(pb + a0); yv0 = *(const float2*)(yb + a0); mv0 = *(const uchar2*)(mb + a0);
    if (ra + 1 < rend) {
      size_t a1 = a0 + W0;
      pv1 = *(const float2*)(pb + a1); yv1 = *(const float2*)(yb + a1); mv1 = *(const uchar2*)(mb + a1);
    } else { pv1 = pv0; yv1 = yv0; mv1 = mv0; }
  }
  for (int r = ra; r < rend; ++r) {
    float2 pv2 = pv1, yv2 = yv1; uchar2 mv2 = mv1;
    if (r + 2 < rend) {
      size_t a2 = (size_t)(r + 2) * W0 + cc;
      pv2 = *(const float2*)(pb + a2); yv2 = *(const float2*)(yb + a2); mv2 = *(const uchar2*)(mb + a2);
    }
    bool core = r < rb;
    float d0 = (pv0.x - mp) * ap - (yv0.x - my) * ay;
    float d1 = (pv0.y - mp) * ap - (yv0.y - my) * ay;
    u8 m0 = mv0.x, m1 = mv0.y;
    float dn = __shfl_down(d0, 1, 64);
    int mn = __shfl_down((int)m0, 1, 64);
    if (vn && edge) {
      size_t a = (size_t)r * W0 + (size_t)cc + 2;
      float pnb = pb[a], ynb = yb[a];
      dn = (pnb - mp) * ap - (ynb - my) * ay;
      mn = mb[a];
    }
    if (act) {
      float f0 = (float)m0, f1 = (float)m1;
      if (core) {
        gx += f0 * f1 * fabsf(d1 - d0); cx += (int)(m0 & m1);
        if (vn) { float fn = (float)mn; gx += f1 * fn * fabsf(dn - d1); cx += (m1 && mn) ? 1 : 0; }
        rr += f0 * fabsf(d0) + f1 * fabsf(d1);
      }
      if (r > ra) {
        gy += f0 * (float)pm0 * fabsf(d0 - pd0); cy += (int)(m0 & pm0);
        gy += f1 * (float)pm1 * fabsf(d1 - pd1); cy += (int)(m1 & pm1);
      }
      if (core && (r & 1)) {
        size_t o = (size_t)img * N1P + (size_t)(r >> 1) * W1S + oc;
        P1[o] = 0.25f * (pd0 + pd1 + d0 + d1);
        M1[o] = (u8)((pm0 | pm1 | m0 | m1) ? 1 : 0);
      }
    }
    pd0 = d0; pd1 = d1; pm0 = m0; pm1 = m1;
    pv0 = pv1; yv0 = yv1; mv0 = mv1;
    pv1 = pv2; yv1 = yv2; mv1 = mv2;
  }
  double v0 = (double)gx, v1 = (double)cx, v2 = (double)gy, v3 = (double)cy, v4 = (double)rr;
  for (int o = 32; o; o >>= 1) {
    v0 += __shfl_down(v0, o, 64); v1 += __shfl_down(v1, o, 64);
    v2 += __shfl_down(v2, o, 64); v3 += __shfl_down(v3, o, 64);
    v4 += __shfl_down(v4, o, 64);
  }
  __shared__ double sh[5][5];
  int wv = threadIdx.x >> 6;
  if (lane == 0) { sh[0][wv] = v0; sh[1][wv] = v1; sh[2][wv] = v2; sh[3][wv] = v3; sh[4][wv] = v4; }
  __syncthreads();
  if (threadIdx.x == 0) {
    double a0 = 0, a1 = 0, a2 = 0, a3 = 0, a4 = 0;
    for (int w = 0; w < 5; w++) { a0 += sh[0][w]; a1 += sh[1][w]; a2 += sh[2][w]; a3 += sh[3][w]; a4 += sh[4][w]; }
    atomicAdd(&gI[img * 4 + 0], a0);
    atomicAdd(&gI[img * 4 + 1], a1);
    atomicAdd(&gI[img * 4 + 2], a2);
    atomicAdd(&gI[img * 4 + 3], a3);
    atomicAdd(&rho[img], a4);
  }
}

// ---------- grad+pool scale 1 (259 -> 129), padded strides, float2 + shfl ----------
__global__ void k_gp(const float* __restrict__ Pin,
    const u8* __restrict__ Min, float* __restrict__ Pout, u8* __restrict__ Mout,
    double* __restrict__ gI)
{
  const int WinL = 259, Hin = 259, WoutL = 129, Hout = 129, nb = 17;
  int img = blockIdx.x / nb, band = blockIdx.x % nb;
  const float* pb = Pin + (size_t)img * N1P;
  const u8* mb = Min + (size_t)img * N1P;
  int poolEnd = 2 * Hout;                         // 258
  int ra = band * 16;
  int rb = min(ra + 16, poolEnd);
  int rbx = (band == nb - 1) ? Hin : rb;
  int rend = (rbx < Hin) ? rbx + 1 : Hin;
  float gx = 0.f, gy = 0.f;
  int cx = 0, cy = 0;
  int oc = threadIdx.x;
  bool act = oc < WoutL;
  int lane = threadIdx.x & 63;
  int c0 = act ? 2 * oc : 0;
  int cn = c0 + 2;
  bool vn = act && (cn < WinL);
  bool gyn = vn && (cn >= 2 * WoutL);             // oc == 128 extra column
  bool direct = vn && ((lane == 63) || (oc == 128));
  float pd0 = 0.f, pd1 = 0.f, pdn = 0.f;
  u8 pm0 = 0, pm1 = 0, pmn = 0;
  for (int r = ra; r < rend; ++r) {
    int base = r * W1S;
    float2 dv = act ? *(const float2*)(pb + base + c0) : make_float2(0.f, 0.f);
    uchar2 mv = act ? *(const uchar2*)(mb + base + c0) : make_uchar2(0, 0);
    float d0 = dv.x, d1 = dv.y;
    u8 m0 = mv.x, m1 = mv.y;
    float dn = __shfl_down(d0, 1, 64);
    int mni = __shfl_down((int)m0, 1, 64);
    if (direct) { dn = pb[base + cn]; mni = mb[base + cn]; }
    u8 mn = (u8)mni;
    bool core = r < rbx;
    if (act) {
      if (core) {
        if (m0 & m1) { gx += fabsf(d1 - d0); cx++; }
        if (vn && (m1 & mn)) { gx += fabsf(dn - d1); cx++; }
      }
      if (r > ra) {
        if (m0 & pm0) { gy += fabsf(d0 - pd0); cy++; }
        if (m1 & pm1) { gy += fabsf(d1 - pd1); cy++; }
        if (gyn && (mn & pmn)) { gy += fabsf(dn - pdn); cy++; }
      }
      if (core && (r & 1) && r < poolEnd) {
        size_t o = (size_t)img * N2P + (size_t)(r >> 1) * W2S + oc;
        Pout[o] = 0.25f * (pd0 + pd1 + d0 + d1);
        Mout[o] = (u8)((pm0 | pm1 | m0 | m1) ? 1 : 0);
      }
    }
    pd0 = d0; pd1 = d1; pdn = dn; pm0 = m0; pm1 = m1; pmn = mn;
  }
  double v0 = (double)gx, v1 = (double)cx, v2 = (double)gy, v3 = (double)cy;
  for (int o = 32; o; o >>= 1) {
    v0 += __shfl_down(v0, o, 64); v1 += __shfl_down(v1, o, 64);
    v2 += __shfl_down(v2, o, 64); v3 += __shfl_down(v3, o, 64);
  }
  __shared__ double sh[4][3];
  int wv = threadIdx.x >> 6;
  if (lane == 0) { sh[0][wv] = v0; sh[1][wv] = v1; sh[2][wv] = v2; sh[3][wv] = v3; }
  __syncthreads();
  if (threadIdx.x == 0) {
    double a0 = sh[0][0] + sh[0][1] + sh[0][2];
    double a1 = sh[1][0] + sh[1][1] + sh[1][2];
    double a2 = sh[2][0] + sh[2][1] + sh[2][2];
    double a3 = sh[3][0] + sh[3][1] + sh[3][2];
    atomicAdd(&gI[img * 4 + 0], a0);
    atomicAdd(&gI[img * 4 + 1], a1);
    atomicAdd(&gI[img * 4 + 2], a2);
    atomicAdd(&gI[img * 4 + 3], a3);
  }
}

// ---------- last level: grad2 (129x129) + in-register pool -> grad3 (64x64) ----------
__global__ __launch_bounds__(64) void k_gp_last(const float* __restrict__ Pin,
    const u8* __restrict__ Min, double* __restrict__ gI2v, double* __restrict__ gI3v)
{
  const int WinL = 129, Hin = 129, Wout = 64, nb = 8;
  int img = blockIdx.x / nb, band = blockIdx.x % nb;
  const float* pb = Pin + (size_t)img * N2P;
  const u8* mb = Min + (size_t)img * N2P;
  int ra = band * 16;
  int rb = min(ra + 16, 128);
  int rbx = (band == nb - 1) ? Hin : rb;
  int rend2 = (band < nb - 1) ? (ra + 18) : Hin;
  float gx = 0.f, gy = 0.f; int cx = 0, cy = 0;
  float ogx = 0.f, ogy = 0.f; int ocx = 0, ocy = 0;
  int oc = threadIdx.x;                      // 0..63
  int c0 = 2 * oc, cn = c0 + 2;
  bool vn = cn < WinL;
  bool gyn = vn && (cn >= 2 * Wout);         // oc == 63
  float pd0 = 0.f, pd1 = 0.f, pdn = 0.f;
  u8 pm0 = 0, pm1 = 0, pmn = 0;
  float ppo = 0.f; int pmo = 0; bool havePrev = false;
  for (int r = ra; r < rend2; ++r) {
    int base = r * W2S;
    float2 dv = *(const float2*)(pb + base + c0);
    uchar2 mv = *(const uchar2*)(mb + base + c0);
    float d0 = dv.x, d1 = dv.y;
    u8 m0 = mv.x, m1 = mv.y;
    float dn = __shfl_down(d0, 1, 64);
    int mni = __shfl_down((int)m0, 1, 64);
    if (vn && oc == 63) { dn = pb[base + cn]; mni = mb[base + cn]; }
    u8 mn = (u8)mni;
    if (r < rbx) {
      if (m0 & m1) { gx += fabsf(d1 - d0); cx++; }
      if (vn && (m1 & mn)) { gx += fabsf(dn - d1); cx++; }
    }
    if (r > ra && r <= rb) {
      if (m0 & pm0) { gy += fabsf(d0 - pd0); cy++; }
      if (m1 & pm1) { gy += fabsf(d1 - pd1); cy++; }
      if (gyn && (mn & pmn)) { gy += fabsf(dn - pdn); cy++; }
    }
    if (r & 1) {
      bool owned = r < rb;
      bool halo = (r == rb + 1);
      if (owned || halo) {
        float po = 0.25f * (pd0 + pd1 + d0 + d1);
        int mo = (pm0 | pm1 | m0 | m1) ? 1 : 0;
        float pon = __shfl_down(po, 1, 64);
        int mon = __shfl_down(mo, 1, 64);
        if (owned && oc < 63 && mo && mon) { ogx += fabsf(pon - po); ocx++; }
        if (havePrev && mo && pmo) { ogy += fabsf(po - ppo); ocy++; }
        ppo = po; pmo = mo; havePrev = true;
      }
    }
    pd0 = d0; pd1 = d1; pdn = dn; pm0 = m0; pm1 = m1; pmn = mn;
  }
  double v[8] = {(double)gx, (double)cx, (double)gy, (double)cy,
                 (double)ogx, (double)ocx, (double)ogy, (double)ocy};
  for (int o = 32; o; o >>= 1)
    for (int k = 0; k < 8; k++) v[k] += __shfl_down(v[k], o, 64);
  if (threadIdx.x == 0) {
    atomicAdd(&gI2v[img * 4 + 0], v[0]);
    atomicAdd(&gI2v[img * 4 + 1], v[1]);
    atomicAdd(&gI2v[img * 4 + 2], v[2]);
    atomicAdd(&gI2v[img * 4 + 3], v[3]);
    atomicAdd(&gI3v[img * 4 + 0], v[4]);
    atomicAdd(&gI3v[img * 4 + 1], v[5]);
    atomicAdd(&gI3v[img * 4 + 2], v[6]);
    atomicAdd(&gI3v[img * 4 + 3], v[7]);
  }
}

// ---------- finalize ----------
__global__ void k_final(const double* __restrict__ rho, const u32* __restrict__ cnt,
    const double* __restrict__ gI0, const double* __restrict__ gI1,
    const double* __restrict__ gI2, const double* __restrict__ gI3,
    float* __restrict__ out)
{
  int i = threadIdx.x;
  double v[17];
  double c = cnt[i] ? (double)cnt[i] : 1.0;
  v[0] = rho[i] / c;
  for (int j = 0; j < 4; j++) {
    v[1 + 0 * 4 + j] = gI0[i * 4 + j];
    v[1 + 1 * 4 + j] = gI1[i * 4 + j];
    v[1 + 2 * 4 + j] = gI2[i * 4 + j];
    v[1 + 3 * 4 + j] = gI3[i * 4 + j];
  }
  for (int o = 32; o; o >>= 1)
    for (int k = 0; k < 17; k++) v[k] += __shfl_down(v[k], o, 64);
  if (i == 0) {
    double ssi = v[0] / (double)NIMG;
    double g = 0.0;
    for (int s = 0; s < 4; s++) {
      double gxs = v[1 + s * 4 + 0], cxs = v[1 + s * 4 + 1];
      double gys = v[1 + s * 4 + 2], cys = v[1 + s * 4 + 3];
      g += gxs / (cxs > 1.0 ? cxs : 1.0);
      g += gys / (cys > 1.0 ? cys : 1.0);
    }
    g /= 4.0;
    out[0] = (float)(ssi + 0.5 * g);
  }
}

extern "C" void kernel_launch(void* const* d_in, const int* in_sizes, int n_in,
                              void* d_out, int out_size, void* d_ws, size_t ws_size,
                              hipStream_t stream) {
  (void)in_sizes; (void)n_in; (void)out_size; (void)ws_size;
  const float4* p4 = (const float4*)d_in[0];
  const float4* y4 = (const float4*)d_in[1];
  const int4* m4 = (const int4*)d_in[2];
  const float* pf = (const float*)d_in[0];
  const float* yf = (const float*)d_in[1];
  u8* ws = (u8*)d_ws;

  u32*    cnt  = (u32*)(ws + OFF_CNT);
  u32*    ccnt = (u32*)(ws + OFF_CCNT);
  u32*    Nbl  = (u32*)(ws + OFF_NBL);
  double* rho  = (double*)(ws + OFF_RHO);
  double* Stot = (double*)(ws + OFF_STOT);
  double* Sbl  = (double*)(ws + OFF_SBL);
  double* gI0  = (double*)(ws + OFF_GI0);
  double* gI1  = (double*)(ws + OFF_GI1);
  double* gI2  = (double*)(ws + OFF_GI2);
  double* gI3  = (double*)(ws + OFF_GI3);
  float*  med  = (float*)(ws + OFF_MED);
  float*  sci  = (float*)(ws + OFF_SCI);
  u32*    selw = (u32*)(ws + OFF_SELW);
  float*  swf  = (float*)(ws + OFF_SWF);
  float*  cand = (float*)(ws + OFF_CAND);
  u8*     mu8  = (u8*)(ws + OFF_MU8);
  float*  P1   = (float*)(ws + OFF_P1);
  u8*     M1   = (u8*)(ws + OFF_M1);
  float*  P2   = (float*)(ws + OFF_P2);
  u8*     M2   = (u8*)(ws + OFF_M2);

  k_sample<<<128, 256, 0, stream>>>(pf, yf, selw, swf, (u32*)ws);
  k_scan0<<<NIMG * BPI, 256, 0, stream>>>(p4, y4, m4, (uchar4*)mu8, swf, cand, ccnt, cnt, Stot, Nbl, Sbl);
  k_med2<<<128, 1024, 0, stream>>>(cand, ccnt, cnt, Nbl, Stot, Sbl, selw, pf, yf, mu8, med, sci);
  k_fuse0<<<NIMG * NB0, 320, 0, stream>>>(pf, yf, mu8, med, sci, P1, M1, rho, gI0);
  k_gp<<<NIMG * 17, 192, 0, stream>>>(P1, M1, P2, M2, gI1);
  k_gp_last<<<NIMG * 8, 64, 0, stream>>>(P2, M2, gI2, gI3);
  k_final<<<1, 64, 0, stream>>>(rho, cnt, gI0, gI1, gI2, gI3, (float*)d_out);
}